// Round 1
// baseline (1807.681 us; speedup 1.0000x reference)
//
#include <hip/hip_runtime.h>
#include <math.h>

#define HGT 100
#define WID 100
#define S_TOK (HGT * WID)          // 10000
#define D_MODEL 256
#define N_HEADS 8
#define DH 32
#define N_POINTS 4
#define N_LAYERS 6
#define BS 2
#define M_TOK (BS * S_TOK)         // 20000

// ---------------------------------------------------------------------------
// Transpose [bs, C, S] -> [bs, S, C]; for pos tensor also add level_embed[c].
// grid: (ceil(S/32), C/32, 4)  z: 0,1 = features b=0,1 ; 2,3 = pos b=0,1
// block: (32, 8)
// ---------------------------------------------------------------------------
__global__ __launch_bounds__(256) void transpose_kernel(
    const float* __restrict__ feat, const float* __restrict__ posin,
    const float* __restrict__ level, float* __restrict__ src,
    float* __restrict__ pos) {
  __shared__ float tile[32][33];
  int which = blockIdx.z;
  int b = which & 1;
  int tsel = which >> 1;
  const float* in = tsel ? posin : feat;
  float* out = tsel ? pos : src;
  int s0 = blockIdx.x * 32;
  int c0 = blockIdx.y * 32;
  int tx = threadIdx.x, ty = threadIdx.y;
#pragma unroll
  for (int i = 0; i < 4; ++i) {
    int c = c0 + ty + i * 8;
    int s = s0 + tx;
    float v = (s < S_TOK) ? in[((size_t)b * D_MODEL + c) * S_TOK + s] : 0.f;
    tile[ty + i * 8][tx] = v;
  }
  __syncthreads();
#pragma unroll
  for (int i = 0; i < 4; ++i) {
    int s = s0 + ty + i * 8;
    int c = c0 + tx;
    if (s < S_TOK) {
      float v = tile[tx][ty + i * 8];
      if (tsel) v += level[c];
      out[((size_t)b * S_TOK + s) * D_MODEL + c] = v;
    }
  }
}

// ---------------------------------------------------------------------------
// fp32 GEMM: C[M,N] = (A (+ A2)) @ W + bias, optional ReLU.
// A: [M,256] row-major, W: [256,N] row-major. BM=BN=64, BK=16, 256 thr, 4x4.
// grid: (ceil(N/64), ceil(M/64))
// ---------------------------------------------------------------------------
template <int ACT>
__global__ __launch_bounds__(256) void gemm_kernel(
    const float* __restrict__ A, const float* __restrict__ A2,
    const float* __restrict__ W, const float* __restrict__ bias,
    float* __restrict__ C, int M, int N) {
  const int K = D_MODEL;
  __shared__ float As[16][68];   // [k][m], padded stride
  __shared__ float Bs[16][64];   // [k][n]
  int bm = blockIdx.y * 64;
  int bn = blockIdx.x * 64;
  int tid = threadIdx.x;
  int tn = tid & 15;        // 0..15 -> n micro
  int tm = tid >> 4;        // 0..15 -> m micro
  // A-tile load mapping: 64 rows x 16 k, float4 per thread
  int lrow = tid >> 2;            // 0..63
  int lk4 = (tid & 3) * 4;        // 0,4,8,12
  // W-tile load mapping: 16 k x 64 n, float4 per thread
  int wk = tid >> 4;              // 0..15
  int wn4 = (tid & 15) * 4;       // 0..60

  float acc[4][4] = {};

  for (int k0 = 0; k0 < K; k0 += 16) {
    int gm = bm + lrow;
    float4 av = make_float4(0.f, 0.f, 0.f, 0.f);
    if (gm < M) {
      av = *reinterpret_cast<const float4*>(A + (size_t)gm * K + k0 + lk4);
      if (A2) {
        float4 pv = *reinterpret_cast<const float4*>(A2 + (size_t)gm * K + k0 + lk4);
        av.x += pv.x; av.y += pv.y; av.z += pv.z; av.w += pv.w;
      }
    }
    As[lk4 + 0][lrow] = av.x;
    As[lk4 + 1][lrow] = av.y;
    As[lk4 + 2][lrow] = av.z;
    As[lk4 + 3][lrow] = av.w;

    float4 wv = make_float4(0.f, 0.f, 0.f, 0.f);
    if (bn + wn4 < N)
      wv = *reinterpret_cast<const float4*>(W + (size_t)(k0 + wk) * N + bn + wn4);
    *reinterpret_cast<float4*>(&Bs[wk][wn4]) = wv;

    __syncthreads();
#pragma unroll
    for (int k = 0; k < 16; ++k) {
      float4 a4 = *reinterpret_cast<const float4*>(&As[k][tm * 4]);
      float4 b4 = *reinterpret_cast<const float4*>(&Bs[k][tn * 4]);
      float aa[4] = {a4.x, a4.y, a4.z, a4.w};
      float bb[4] = {b4.x, b4.y, b4.z, b4.w};
#pragma unroll
      for (int i = 0; i < 4; ++i)
#pragma unroll
        for (int j = 0; j < 4; ++j) acc[i][j] = fmaf(aa[i], bb[j], acc[i][j]);
    }
    __syncthreads();
  }

  int gn = bn + tn * 4;
  if (gn < N) {
    float4 bb4 = *reinterpret_cast<const float4*>(bias + gn);
    float bb[4] = {bb4.x, bb4.y, bb4.z, bb4.w};
#pragma unroll
    for (int i = 0; i < 4; ++i) {
      int gm = bm + tm * 4 + i;
      if (gm < M) {
        float4 o;
        float v0 = acc[i][0] + bb[0];
        float v1 = acc[i][1] + bb[1];
        float v2 = acc[i][2] + bb[2];
        float v3 = acc[i][3] + bb[3];
        if (ACT) {
          v0 = fmaxf(v0, 0.f); v1 = fmaxf(v1, 0.f);
          v2 = fmaxf(v2, 0.f); v3 = fmaxf(v3, 0.f);
        }
        o.x = v0; o.y = v1; o.z = v2; o.w = v3;
        *reinterpret_cast<float4*>(C + (size_t)gm * N + gn) = o;
      }
    }
  }
}

// ---------------------------------------------------------------------------
// Softmax over last dim (4) of [M_TOK, HEADS, 4]; in-place. 1 thread per row.
// ---------------------------------------------------------------------------
__global__ __launch_bounds__(256) void softmax4_kernel(float* __restrict__ aw,
                                                       int n) {
  int i = blockIdx.x * blockDim.x + threadIdx.x;
  if (i >= n) return;
  float4 v = *reinterpret_cast<const float4*>(aw + (size_t)i * 4);
  float m = fmaxf(fmaxf(v.x, v.y), fmaxf(v.z, v.w));
  float e0 = expf(v.x - m), e1 = expf(v.y - m);
  float e2 = expf(v.z - m), e3 = expf(v.w - m);
  float inv = 1.f / (e0 + e1 + e2 + e3);
  float4 o = make_float4(e0 * inv, e1 * inv, e2 * inv, e3 * inv);
  *reinterpret_cast<float4*>(aw + (size_t)i * 4) = o;
}

// ---------------------------------------------------------------------------
// Deformable sampling + attention-weight combine.
// One block (256 thr = 8 heads x 32 dh) per token.
// attn[token, h*32+dh] = sum_p attw[t,h,p] * bilinear(value[b,:,h,:], loc)
// Pixel coords: px = x + off_x, py = y + off_y (align_corners=False algebra).
// ---------------------------------------------------------------------------
__global__ __launch_bounds__(256) void sample_kernel(
    const float* __restrict__ value, const float* __restrict__ off,
    const float* __restrict__ attw, float* __restrict__ attn) {
  __shared__ float loff[64];
  __shared__ float lw[32];
  int token = blockIdx.x;
  int tid = threadIdx.x;
  if (tid < 64) loff[tid] = off[(size_t)token * 64 + tid];
  else if (tid < 96) lw[tid - 64] = attw[(size_t)token * 32 + (tid - 64)];
  __syncthreads();

  int h = tid >> 5;
  int dh = tid & 31;
  int b = token / S_TOK;
  int s = token - b * S_TOK;
  int ix = s % WID;
  int iy = s / WID;
  const float* vbase = value + ((size_t)b * S_TOK) * D_MODEL + h * DH + dh;

  float acc = 0.f;
#pragma unroll
  for (int p = 0; p < N_POINTS; ++p) {
    float ox = loff[h * 8 + p * 2 + 0];
    float oy = loff[h * 8 + p * 2 + 1];
    float aw = lw[h * 4 + p];
    float px = (float)ix + ox;
    float py = (float)iy + oy;
    float x0f = floorf(px), y0f = floorf(py);
    int x0 = (int)x0f, y0 = (int)y0f;
    float wx1 = px - x0f, wx0 = 1.f - wx1;
    float wy1 = py - y0f, wy0 = 1.f - wy1;
    float sv = 0.f;
    if (x0 >= 0 && x0 < WID && y0 >= 0 && y0 < HGT)
      sv = fmaf(wx0 * wy0, vbase[(size_t)(y0 * WID + x0) * D_MODEL], sv);
    if (x0 + 1 >= 0 && x0 + 1 < WID && y0 >= 0 && y0 < HGT)
      sv = fmaf(wx1 * wy0, vbase[(size_t)(y0 * WID + x0 + 1) * D_MODEL], sv);
    if (x0 >= 0 && x0 < WID && y0 + 1 >= 0 && y0 + 1 < HGT)
      sv = fmaf(wx0 * wy1, vbase[(size_t)((y0 + 1) * WID + x0) * D_MODEL], sv);
    if (x0 + 1 >= 0 && x0 + 1 < WID && y0 + 1 >= 0 && y0 + 1 < HGT)
      sv = fmaf(wx1 * wy1, vbase[(size_t)((y0 + 1) * WID + x0 + 1) * D_MODEL], sv);
    acc = fmaf(aw, sv, acc);
  }
  attn[(size_t)token * D_MODEL + h * DH + dh] = acc;
}

// ---------------------------------------------------------------------------
// LayerNorm(x + add) * g + b -> out. One 64-lane wave per 256-float row,
// 4 rows per 256-thread block.
// ---------------------------------------------------------------------------
__global__ __launch_bounds__(256) void ln_kernel(
    const float* __restrict__ x, const float* __restrict__ add,
    const float* __restrict__ g, const float* __restrict__ b,
    float* __restrict__ out, int M) {
  int row = blockIdx.x * 4 + (threadIdx.x >> 6);
  if (row >= M) return;
  int lane = threadIdx.x & 63;
  float4 xv = *reinterpret_cast<const float4*>(x + (size_t)row * 256 + lane * 4);
  float4 av = *reinterpret_cast<const float4*>(add + (size_t)row * 256 + lane * 4);
  float v0 = xv.x + av.x, v1 = xv.y + av.y, v2 = xv.z + av.z, v3 = xv.w + av.w;
  float sum = v0 + v1 + v2 + v3;
  float sq = v0 * v0 + v1 * v1 + v2 * v2 + v3 * v3;
#pragma unroll
  for (int o = 32; o; o >>= 1) {
    sum += __shfl_xor(sum, o);
    sq += __shfl_xor(sq, o);
  }
  float mean = sum * (1.f / 256.f);
  float var = sq * (1.f / 256.f) - mean * mean;
  float rs = rsqrtf(var + 1e-5f);
  float4 gv = *reinterpret_cast<const float4*>(g + lane * 4);
  float4 bv = *reinterpret_cast<const float4*>(b + lane * 4);
  float4 o;
  o.x = (v0 - mean) * rs * gv.x + bv.x;
  o.y = (v1 - mean) * rs * gv.y + bv.y;
  o.z = (v2 - mean) * rs * gv.z + bv.z;
  o.w = (v3 - mean) * rs * gv.w + bv.w;
  *reinterpret_cast<float4*>(out + (size_t)row * 256 + lane * 4) = o;
}

// ---------------------------------------------------------------------------
extern "C" void kernel_launch(void* const* d_in, const int* in_sizes, int n_in,
                              void* d_out, int out_size, void* d_ws,
                              size_t ws_size, hipStream_t stream) {
  const float* features  = (const float*)d_in[0];
  const float* pos_embed = (const float*)d_in[1];
  const float* level_emb = (const float*)d_in[2];
  const float* off_w = (const float*)d_in[3];
  const float* off_b = (const float*)d_in[4];
  const float* aw_w  = (const float*)d_in[5];
  const float* aw_b  = (const float*)d_in[6];
  const float* val_w = (const float*)d_in[7];
  const float* val_b = (const float*)d_in[8];
  const float* out_w = (const float*)d_in[9];
  const float* out_b = (const float*)d_in[10];
  const float* ln1_g = (const float*)d_in[11];
  const float* ln1_b = (const float*)d_in[12];
  const float* ffn_w1 = (const float*)d_in[13];
  const float* ffn_b1 = (const float*)d_in[14];
  const float* ffn_w2 = (const float*)d_in[15];
  const float* ffn_b2 = (const float*)d_in[16];
  const float* ln3_g = (const float*)d_in[17];
  const float* ln3_b = (const float*)d_in[18];

  float* ws = (float*)d_ws;
  const size_t BIG = (size_t)M_TOK * D_MODEL;  // 5.12M floats
  float* src   = ws;                 // [M_TOK, 256]
  float* pos   = src + BIG;          // [M_TOK, 256]
  float* value = pos + BIG;          // [M_TOK, 256]; reused as FFN hidden
  float* attn  = value + BIG;        // [M_TOK, 256]
  float* offb  = attn + BIG;         // [M_TOK, 64]
  float* attwb = offb + (size_t)M_TOK * 64;  // [M_TOK, 32]
  float* tmp   = (float*)d_out;      // [M_TOK, 256] post-GEMM scratch

  transpose_kernel<<<dim3(313, 8, 4), dim3(32, 8), 0, stream>>>(
      features, pos_embed, level_emb, src, pos);

  for (int l = 0; l < N_LAYERS; ++l) {
    const float* vw = val_w + (size_t)l * 256 * 256;
    const float* vb = val_b + (size_t)l * 256;
    const float* ow = off_w + (size_t)l * 256 * 64;
    const float* ob = off_b + (size_t)l * 64;
    const float* awl = aw_w + (size_t)l * 256 * 32;
    const float* abl = aw_b + (size_t)l * 32;
    const float* uw = out_w + (size_t)l * 256 * 256;
    const float* ub = out_b + (size_t)l * 256;
    const float* w1 = ffn_w1 + (size_t)l * 256 * 256;
    const float* b1 = ffn_b1 + (size_t)l * 256;
    const float* w2 = ffn_w2 + (size_t)l * 256 * 256;
    const float* b2 = ffn_b2 + (size_t)l * 256;

    gemm_kernel<0><<<dim3(4, 313), 256, 0, stream>>>(src, nullptr, vw, vb,
                                                     value, M_TOK, 256);
    gemm_kernel<0><<<dim3(1, 313), 256, 0, stream>>>(src, pos, ow, ob, offb,
                                                     M_TOK, 64);
    gemm_kernel<0><<<dim3(1, 313), 256, 0, stream>>>(src, pos, awl, abl, attwb,
                                                     M_TOK, 32);
    softmax4_kernel<<<dim3(625), 256, 0, stream>>>(attwb, M_TOK * N_HEADS);
    sample_kernel<<<dim3(M_TOK), 256, 0, stream>>>(value, offb, attwb, attn);
    gemm_kernel<0><<<dim3(4, 313), 256, 0, stream>>>(attn, nullptr, uw, ub, tmp,
                                                     M_TOK, 256);
    ln_kernel<<<dim3(5000), 256, 0, stream>>>(src, tmp, ln1_g + l * 256,
                                              ln1_b + l * 256, src, M_TOK);
    gemm_kernel<1><<<dim3(4, 313), 256, 0, stream>>>(src, nullptr, w1, b1,
                                                     value, M_TOK, 256);
    gemm_kernel<0><<<dim3(4, 313), 256, 0, stream>>>(value, nullptr, w2, b2,
                                                     tmp, M_TOK, 256);
    ln_kernel<<<dim3(5000), 256, 0, stream>>>(
        src, tmp, ln3_g + l * 256, ln3_b + l * 256,
        (l == N_LAYERS - 1) ? (float*)d_out : src, M_TOK);
  }
}

// Round 3
// 940.227 us; speedup vs baseline: 1.9226x; 1.9226x over previous
//
#include <hip/hip_runtime.h>
#include <math.h>

#define HGT 100
#define WID 100
#define S_TOK (HGT * WID)          // 10000
#define D_MODEL 256
#define N_HEADS 8
#define DH 32
#define N_POINTS 4
#define N_LAYERS 6
#define BS 2
#define M_TOK (BS * S_TOK)         // 20000

typedef __attribute__((ext_vector_type(8))) short short8v;   // 8 bf16 = 4 VGPR
typedef __attribute__((ext_vector_type(4))) float f32x4;

__device__ __forceinline__ short f2bf(float f) {
  union { float f; unsigned u; } v; v.f = f;
  unsigned r = v.u + 0x7fff + ((v.u >> 16) & 1);   // round-to-nearest-even
  return (short)(r >> 16);
}

// ---------------------------------------------------------------------------
// Transpose [bs, C, S] -> [bs, S, C]; for pos tensor also add level_embed[c].
// grid: (ceil(S/32), C/32, 4)  z: 0,1 = features b=0,1 ; 2,3 = pos b=0,1
// ---------------------------------------------------------------------------
__global__ __launch_bounds__(256) void transpose_kernel(
    const float* __restrict__ feat, const float* __restrict__ posin,
    const float* __restrict__ level, float* __restrict__ src,
    float* __restrict__ pos) {
  __shared__ float tile[32][33];
  int which = blockIdx.z;
  int b = which & 1;
  int tsel = which >> 1;
  const float* in = tsel ? posin : feat;
  float* out = tsel ? pos : src;
  int s0 = blockIdx.x * 32;
  int c0 = blockIdx.y * 32;
  int tx = threadIdx.x, ty = threadIdx.y;
#pragma unroll
  for (int i = 0; i < 4; ++i) {
    int c = c0 + ty + i * 8;
    int s = s0 + tx;
    float v = (s < S_TOK) ? in[((size_t)b * D_MODEL + c) * S_TOK + s] : 0.f;
    tile[ty + i * 8][tx] = v;
  }
  __syncthreads();
#pragma unroll
  for (int i = 0; i < 4; ++i) {
    int s = s0 + ty + i * 8;
    int c = c0 + tx;
    if (s < S_TOK) {
      float v = tile[tx][ty + i * 8];
      if (tsel) v += level[c];
      out[((size_t)b * S_TOK + s) * D_MODEL + c] = v;
    }
  }
}

// ---------------------------------------------------------------------------
// Weight transpose + fp32->bf16: src [L][K=256][N] -> dst [L][N][256] bf16.
// grid ((N+31)/32, 8, L), block (32,8)
// ---------------------------------------------------------------------------
__global__ __launch_bounds__(256) void convT_kernel(
    const float* __restrict__ src, short* __restrict__ dst, int N,
    size_t srcLS, size_t dstLS) {
  __shared__ float t[32][33];
  int l = blockIdx.z;
  const float* s = src + (size_t)l * srcLS;
  short* d = dst + (size_t)l * dstLS;
  int n0 = blockIdx.x * 32, k0 = blockIdx.y * 32;
  int tx = threadIdx.x, ty = threadIdx.y;
#pragma unroll
  for (int i = 0; i < 4; ++i) {
    int k = k0 + ty + i * 8;
    int n = n0 + tx;
    t[ty + i * 8][tx] = (n < N) ? s[(size_t)k * N + n] : 0.f;
  }
  __syncthreads();
#pragma unroll
  for (int i = 0; i < 4; ++i) {
    int n = n0 + ty + i * 8;
    int k = k0 + tx;
    if (n < N) d[(size_t)n * 256 + k] = f2bf(t[tx][ty + i * 8]);
  }
}

// Concat off_b [L][64] + aw_b [L][32] -> bias96 [L][96]
__global__ void biascat_kernel(const float* __restrict__ ob,
                               const float* __restrict__ ab,
                               float* __restrict__ dst) {
  int l = blockIdx.x, i = threadIdx.x;
  dst[l * 96 + i] = (i < 64) ? ob[l * 64 + i] : ab[l * 32 + (i - 64)];
}

// ---------------------------------------------------------------------------
// bf16 MFMA GEMM: C[M,N] = (A (+A2)) @ W + bias  (W given transposed [N][256]
// bf16). BM=BN=128, BK=32, 256 thr = 4 waves; wave w computes rows w*32..+31
// x all 128 cols via 2x8 16x16 frags. fp32 accumulate, fp32 C. ACT=1: ReLU.
// LDS rows padded to 40 shorts (80 B) -> ds_read_b128 2-way (free).
// ---------------------------------------------------------------------------
#define LDSP 40
template <int ACT>
__global__ __launch_bounds__(256) void mfma_gemm(
    const float* __restrict__ A, const float* __restrict__ A2,
    const short* __restrict__ WT, const float* __restrict__ bias,
    float* __restrict__ C, int M, int N) {
  const int K = D_MODEL;
  __shared__ short As[128 * LDSP];
  __shared__ short Bs[128 * LDSP];
  int tid = threadIdx.x;
  int wave = tid >> 6, lane = tid & 63;
  int lr = lane & 15, kb = lane >> 4;
  int bm = blockIdx.y * 128, bn = blockIdx.x * 128;

  // staging map: thread t handles row t>>1, k-half (t&1)*16 (16 elements)
  int srow = tid >> 1;
  int skh = (tid & 1) << 4;
  int gm = bm + srow;
  bool aok = gm < M;
  const float* aptr = A + (size_t)gm * K + skh;
  const float* a2ptr = A2 ? (A2 + (size_t)gm * K + skh) : nullptr;
  int gn = bn + srow;
  bool bok = gn < N;
  const short* bptr = WT + (size_t)gn * K + skh;
  short* asd = &As[srow * LDSP + skh];
  short* bsd = &Bs[srow * LDSP + skh];

  f32x4 acc[2][8] = {};

  for (int k0 = 0; k0 < K; k0 += 32) {
    // ---- stage A (fp32 -> bf16) ----
    float av[16];
#pragma unroll
    for (int j = 0; j < 4; ++j) {
      float4 v = aok ? *reinterpret_cast<const float4*>(aptr + k0 + j * 4)
                     : make_float4(0.f, 0.f, 0.f, 0.f);
      av[j * 4 + 0] = v.x; av[j * 4 + 1] = v.y;
      av[j * 4 + 2] = v.z; av[j * 4 + 3] = v.w;
    }
    if (a2ptr && aok) {
#pragma unroll
      for (int j = 0; j < 4; ++j) {
        float4 v = *reinterpret_cast<const float4*>(a2ptr + k0 + j * 4);
        av[j * 4 + 0] += v.x; av[j * 4 + 1] += v.y;
        av[j * 4 + 2] += v.z; av[j * 4 + 3] += v.w;
      }
    }
    short8v ap0, ap1;
#pragma unroll
    for (int j = 0; j < 8; ++j) { ap0[j] = f2bf(av[j]); ap1[j] = f2bf(av[8 + j]); }
    *reinterpret_cast<short8v*>(asd) = ap0;
    *reinterpret_cast<short8v*>(asd + 8) = ap1;
    // ---- stage B (bf16 copy) ----
    short8v b0 = {}, b1 = {};
    if (bok) {
      b0 = *reinterpret_cast<const short8v*>(bptr + k0);
      b1 = *reinterpret_cast<const short8v*>(bptr + k0 + 8);
    }
    *reinterpret_cast<short8v*>(bsd) = b0;
    *reinterpret_cast<short8v*>(bsd + 8) = b1;

    __syncthreads();
    short8v af[2], bfr[8];
#pragma unroll
    for (int i = 0; i < 2; ++i)
      af[i] = *reinterpret_cast<const short8v*>(
          &As[(wave * 32 + i * 16 + lr) * LDSP + kb * 8]);
#pragma unroll
    for (int j = 0; j < 8; ++j)
      bfr[j] = *reinterpret_cast<const short8v*>(
          &Bs[(j * 16 + lr) * LDSP + kb * 8]);
#pragma unroll
    for (int i = 0; i < 2; ++i)
#pragma unroll
      for (int j = 0; j < 8; ++j)
        acc[i][j] = __builtin_amdgcn_mfma_f32_16x16x32_bf16(af[i], bfr[j],
                                                            acc[i][j], 0, 0, 0);
    __syncthreads();
  }

  // ---- epilogue: D col = lane&15, row = (lane>>4)*4 + i ----
#pragma unroll
  for (int fn = 0; fn < 8; ++fn) {
    int c = bn + fn * 16 + lr;
    if (c >= N) continue;
    float bv = bias[c];
#pragma unroll
    for (int fm = 0; fm < 2; ++fm) {
#pragma unroll
      for (int i = 0; i < 4; ++i) {
        int r = bm + wave * 32 + fm * 16 + kb * 4 + i;
        if (r < M) {
          float v = acc[fm][fn][i] + bv;
          if (ACT) v = fmaxf(v, 0.f);
          C[(size_t)r * N + c] = v;
        }
      }
    }
  }
}

// ---------------------------------------------------------------------------
// Deformable sampling, fused softmax. 4 tokens per 256-thr block; per token:
// 64 lanes = 8 heads x 8 dh-quads (float4). XCD-chunked block swizzle.
// offaw: [M,96] = 64 raw offsets + 32 raw attention logits per token.
// ---------------------------------------------------------------------------
__global__ __launch_bounds__(256) void sample_kernel(
    const float* __restrict__ value, const float* __restrict__ offaw,
    float* __restrict__ attn) {
  __shared__ float loff[4][64];
  __shared__ float lw[4][32];
  int bid = blockIdx.x;
  int chunk = gridDim.x >> 3;                      // 5000/8 = 625
  int swz = (bid & 7) * chunk + (bid >> 3);
  int tok0 = swz * 4;
  int tid = threadIdx.x;
  for (int i = tid; i < 384; i += 256) {
    int t = i / 96, j = i - t * 96;
    float v = offaw[(size_t)(tok0 + t) * 96 + j];
    if (j < 64) loff[t][j] = v; else lw[t][j - 64] = v;
  }
  __syncthreads();
  if (tid < 32) {                                   // softmax over 4 points
    int t = tid >> 3, h = tid & 7;
    float* w = &lw[t][h * 4];
    float m = fmaxf(fmaxf(w[0], w[1]), fmaxf(w[2], w[3]));
    float e0 = __expf(w[0] - m), e1 = __expf(w[1] - m);
    float e2 = __expf(w[2] - m), e3 = __expf(w[3] - m);
    float inv = 1.f / (e0 + e1 + e2 + e3);
    w[0] = e0 * inv; w[1] = e1 * inv; w[2] = e2 * inv; w[3] = e3 * inv;
  }
  __syncthreads();

  int ts = tid >> 6, lane = tid & 63;
  int token = tok0 + ts;
  int h = lane >> 3, d4 = (lane & 7) * 4;
  int b = token / S_TOK;
  int s = token - b * S_TOK;
  int ix = s % WID, iy = s / WID;
  const float* vbase = value + ((size_t)b * S_TOK) * D_MODEL + h * DH + d4;

  float4 acc = make_float4(0.f, 0.f, 0.f, 0.f);
#pragma unroll
  for (int p = 0; p < N_POINTS; ++p) {
    float ox = loff[ts][h * 8 + p * 2 + 0];
    float oy = loff[ts][h * 8 + p * 2 + 1];
    float aw = lw[ts][h * 4 + p];
    float px = (float)ix + ox;
    float py = (float)iy + oy;
    float x0f = floorf(px), y0f = floorf(py);
    int x0 = (int)x0f, y0 = (int)y0f;
    float wx1 = px - x0f, wx0 = 1.f - wx1;
    float wy1 = py - y0f, wy0 = 1.f - wy1;
    float4 sv = make_float4(0.f, 0.f, 0.f, 0.f);
    bool xa = (x0 >= 0) & (x0 < WID), xb = (x0 + 1 >= 0) & (x0 + 1 < WID);
    bool ya = (y0 >= 0) & (y0 < HGT), yb = (y0 + 1 >= 0) & (y0 + 1 < HGT);
#define CORNER(XOK, YOK, XI, YI, WGT)                                        \
    if ((XOK) & (YOK)) {                                                     \
      float4 v = *reinterpret_cast<const float4*>(                           \
          vbase + (size_t)((YI) * WID + (XI)) * D_MODEL);                    \
      sv.x = fmaf(WGT, v.x, sv.x); sv.y = fmaf(WGT, v.y, sv.y);              \
      sv.z = fmaf(WGT, v.z, sv.z); sv.w = fmaf(WGT, v.w, sv.w);              \
    }
    CORNER(xa, ya, x0, y0, wx0 * wy0)
    CORNER(xb, ya, x0 + 1, y0, wx1 * wy0)
    CORNER(xa, yb, x0, y0 + 1, wx0 * wy1)
    CORNER(xb, yb, x0 + 1, y0 + 1, wx1 * wy1)
#undef CORNER
    acc.x = fmaf(aw, sv.x, acc.x); acc.y = fmaf(aw, sv.y, acc.y);
    acc.z = fmaf(aw, sv.z, acc.z); acc.w = fmaf(aw, sv.w, acc.w);
  }
  *reinterpret_cast<float4*>(attn + (size_t)token * D_MODEL + h * DH + d4) = acc;
}

// ---------------------------------------------------------------------------
// LayerNorm(x + add) * g + b -> out. One wave per 256-float row.
// ---------------------------------------------------------------------------
__global__ __launch_bounds__(256) void ln_kernel(
    const float* __restrict__ x, const float* __restrict__ add,
    const float* __restrict__ g, const float* __restrict__ b,
    float* __restrict__ out, int M) {
  int row = blockIdx.x * 4 + (threadIdx.x >> 6);
  if (row >= M) return;
  int lane = threadIdx.x & 63;
  float4 xv = *reinterpret_cast<const float4*>(x + (size_t)row * 256 + lane * 4);
  float4 av = *reinterpret_cast<const float4*>(add + (size_t)row * 256 + lane * 4);
  float v0 = xv.x + av.x, v1 = xv.y + av.y, v2 = xv.z + av.z, v3 = xv.w + av.w;
  float sum = v0 + v1 + v2 + v3;
  float sq = v0 * v0 + v1 * v1 + v2 * v2 + v3 * v3;
#pragma unroll
  for (int o = 32; o; o >>= 1) {
    sum += __shfl_xor(sum, o);
    sq += __shfl_xor(sq, o);
  }
  float mean = sum * (1.f / 256.f);
  float var = sq * (1.f / 256.f) - mean * mean;
  float rs = rsqrtf(var + 1e-5f);
  float4 gv = *reinterpret_cast<const float4*>(g + lane * 4);
  float4 bv = *reinterpret_cast<const float4*>(b + lane * 4);
  float4 o;
  o.x = (v0 - mean) * rs * gv.x + bv.x;
  o.y = (v1 - mean) * rs * gv.y + bv.y;
  o.z = (v2 - mean) * rs * gv.z + bv.z;
  o.w = (v3 - mean) * rs * gv.w + bv.w;
  *reinterpret_cast<float4*>(out + (size_t)row * 256 + lane * 4) = o;
}

// ---------------------------------------------------------------------------
extern "C" void kernel_launch(void* const* d_in, const int* in_sizes, int n_in,
                              void* d_out, int out_size, void* d_ws,
                              size_t ws_size, hipStream_t stream) {
  const float* features  = (const float*)d_in[0];
  const float* pos_embed = (const float*)d_in[1];
  const float* level_emb = (const float*)d_in[2];
  const float* off_w = (const float*)d_in[3];
  const float* off_b = (const float*)d_in[4];
  const float* aw_w  = (const float*)d_in[5];
  const float* aw_b  = (const float*)d_in[6];
  const float* val_w = (const float*)d_in[7];
  const float* val_b = (const float*)d_in[8];
  const float* out_w = (const float*)d_in[9];
  const float* out_b = (const float*)d_in[10];
  const float* ln1_g = (const float*)d_in[11];
  const float* ln1_b = (const float*)d_in[12];
  const float* ffn_w1 = (const float*)d_in[13];
  const float* ffn_b1 = (const float*)d_in[14];
  const float* ffn_w2 = (const float*)d_in[15];
  const float* ffn_b2 = (const float*)d_in[16];
  const float* ln3_g = (const float*)d_in[17];
  const float* ln3_b = (const float*)d_in[18];

  float* ws = (float*)d_ws;
  const size_t BIG = (size_t)M_TOK * D_MODEL;  // 5.12M floats
  float* src   = ws;                       // [M,256]
  float* pos   = src + BIG;                // [M,256]
  float* value = pos + BIG;                // [M,256]; reused as FFN hidden
  float* attn  = value + BIG;              // [M,256]
  float* offaw = attn + BIG;               // [M,96]
  float* fend  = offaw + (size_t)M_TOK * 96;
  short* wv  = (short*)fend;               // [6][256][256] bf16 (W^T)
  short* wo  = wv + (size_t)6 * 65536;
  short* w1t = wo + (size_t)6 * 65536;
  short* w2t = w1t + (size_t)6 * 65536;
  short* woa = w2t + (size_t)6 * 65536;    // [6][96][256] bf16
  float* bias96 = (float*)(woa + (size_t)6 * 96 * 256);  // [6][96]
  float* tmp = (float*)d_out;              // [M,256] post-GEMM scratch

  transpose_kernel<<<dim3(313, 8, 4), dim3(32, 8), 0, stream>>>(
      features, pos_embed, level_emb, src, pos);
  convT_kernel<<<dim3(8, 8, 6), dim3(32, 8), 0, stream>>>(val_w, wv, 256,
                                                          65536, 65536);
  convT_kernel<<<dim3(8, 8, 6), dim3(32, 8), 0, stream>>>(out_w, wo, 256,
                                                          65536, 65536);
  convT_kernel<<<dim3(8, 8, 6), dim3(32, 8), 0, stream>>>(ffn_w1, w1t, 256,
                                                          65536, 65536);
  convT_kernel<<<dim3(8, 8, 6), dim3(32, 8), 0, stream>>>(ffn_w2, w2t, 256,
                                                          65536, 65536);
  convT_kernel<<<dim3(2, 8, 6), dim3(32, 8), 0, stream>>>(
      off_w, woa, 64, (size_t)256 * 64, (size_t)96 * 256);
  convT_kernel<<<dim3(1, 8, 6), dim3(32, 8), 0, stream>>>(
      aw_w, woa + (size_t)64 * 256, 32, (size_t)256 * 32, (size_t)96 * 256);
  biascat_kernel<<<dim3(6), dim3(96), 0, stream>>>(off_b, aw_b, bias96);

  for (int l = 0; l < N_LAYERS; ++l) {
    const short* wvl = wv + (size_t)l * 65536;
    const short* wol = wo + (size_t)l * 65536;
    const short* w1l = w1t + (size_t)l * 65536;
    const short* w2l = w2t + (size_t)l * 65536;
    const short* woal = woa + (size_t)l * 96 * 256;

    mfma_gemm<0><<<dim3(2, 157), 256, 0, stream>>>(
        src, nullptr, wvl, val_b + (size_t)l * 256, value, M_TOK, 256);
    mfma_gemm<0><<<dim3(1, 157), 256, 0, stream>>>(
        src, pos, woal, bias96 + (size_t)l * 96, offaw, M_TOK, 96);
    sample_kernel<<<dim3(M_TOK / 4), 256, 0, stream>>>(value, offaw, attn);
    mfma_gemm<0><<<dim3(2, 157), 256, 0, stream>>>(
        attn, nullptr, wol, out_b + (size_t)l * 256, tmp, M_TOK, 256);
    ln_kernel<<<dim3(5000), 256, 0, stream>>>(src, tmp, ln1_g + l * 256,
                                              ln1_b + l * 256, src, M_TOK);
    mfma_gemm<1><<<dim3(2, 157), 256, 0, stream>>>(
        src, nullptr, w1l, ffn_b1 + (size_t)l * 256, value, M_TOK, 256);
    mfma_gemm<0><<<dim3(2, 157), 256, 0, stream>>>(
        value, nullptr, w2l, ffn_b2 + (size_t)l * 256, tmp, M_TOK, 256);
    ln_kernel<<<dim3(5000), 256, 0, stream>>>(
        src, tmp, ln3_g + l * 256, ln3_b + l * 256,
        (l == N_LAYERS - 1) ? (float*)d_out : src, M_TOK);
  }
}

// Round 4
// 843.394 us; speedup vs baseline: 2.1433x; 1.1148x over previous
//
#include <hip/hip_runtime.h>
#include <math.h>

#define HGT 100
#define WID 100
#define S_TOK (HGT * WID)          // 10000
#define D_MODEL 256
#define N_HEADS 8
#define DH 32
#define N_POINTS 4
#define N_LAYERS 6
#define BS 2
#define M_TOK (BS * S_TOK)         // 20000

typedef __attribute__((ext_vector_type(8))) short short8v;   // 8 bf16 = 16 B
typedef __attribute__((ext_vector_type(4))) short short4v;   // 4 bf16 = 8 B
typedef __attribute__((ext_vector_type(4))) float f32x4;

__device__ __forceinline__ short f2bf(float f) {
  union { float f; unsigned u; } v; v.f = f;
  unsigned r = v.u + 0x7fff + ((v.u >> 16) & 1);   // round-to-nearest-even
  return (short)(r >> 16);
}
__device__ __forceinline__ float bf2f(short s) {
  union { unsigned u; float f; } v;
  v.u = ((unsigned)(unsigned short)s) << 16;
  return v.f;
}

// ---------------------------------------------------------------------------
// Transpose [bs, C, S] -> [bs, S, C]. z: 0,1 = features b (fp32 out src);
// 2,3 = pos b (bf16 out posb, + level_embed).
// ---------------------------------------------------------------------------
__global__ __launch_bounds__(256) void transpose_kernel(
    const float* __restrict__ feat, const float* __restrict__ posin,
    const float* __restrict__ level, float* __restrict__ src,
    short* __restrict__ posb) {
  __shared__ float tile[32][33];
  int which = blockIdx.z;
  int b = which & 1;
  int tsel = which >> 1;
  const float* in = tsel ? posin : feat;
  int s0 = blockIdx.x * 32;
  int c0 = blockIdx.y * 32;
  int tx = threadIdx.x, ty = threadIdx.y;
#pragma unroll
  for (int i = 0; i < 4; ++i) {
    int c = c0 + ty + i * 8;
    int s = s0 + tx;
    float v = (s < S_TOK) ? in[((size_t)b * D_MODEL + c) * S_TOK + s] : 0.f;
    tile[ty + i * 8][tx] = v;
  }
  __syncthreads();
#pragma unroll
  for (int i = 0; i < 4; ++i) {
    int s = s0 + ty + i * 8;
    int c = c0 + tx;
    if (s < S_TOK) {
      float v = tile[tx][ty + i * 8];
      size_t o = ((size_t)b * S_TOK + s) * D_MODEL + c;
      if (tsel) posb[o] = f2bf(v + level[c]);
      else src[o] = v;
    }
  }
}

// srcb = bf16(src); qb = bf16(src + posb). 4 elems/thread, grid 5000.
__global__ __launch_bounds__(256) void pack_kernel(
    const float* __restrict__ src, const short* __restrict__ posb,
    short* __restrict__ srcb, short* __restrict__ qb) {
  int i = (blockIdx.x * 256 + threadIdx.x) * 4;
  float4 s = *reinterpret_cast<const float4*>(src + i);
  short4v p = *reinterpret_cast<const short4v*>(posb + i);
  short4v sb, q;
  sb[0] = f2bf(s.x); sb[1] = f2bf(s.y); sb[2] = f2bf(s.z); sb[3] = f2bf(s.w);
  q[0] = f2bf(s.x + bf2f(p[0])); q[1] = f2bf(s.y + bf2f(p[1]));
  q[2] = f2bf(s.z + bf2f(p[2])); q[3] = f2bf(s.w + bf2f(p[3]));
  *reinterpret_cast<short4v*>(srcb + i) = sb;
  *reinterpret_cast<short4v*>(qb + i) = q;
}

// ---------------------------------------------------------------------------
// Weight transpose + fp32->bf16: src [L][K=256][N] -> dst [L][N][256] bf16.
// ---------------------------------------------------------------------------
__global__ __launch_bounds__(256) void convT_kernel(
    const float* __restrict__ src, short* __restrict__ dst, int N,
    size_t srcLS, size_t dstLS) {
  __shared__ float t[32][33];
  int l = blockIdx.z;
  const float* s = src + (size_t)l * srcLS;
  short* d = dst + (size_t)l * dstLS;
  int n0 = blockIdx.x * 32, k0 = blockIdx.y * 32;
  int tx = threadIdx.x, ty = threadIdx.y;
#pragma unroll
  for (int i = 0; i < 4; ++i) {
    int k = k0 + ty + i * 8;
    int n = n0 + tx;
    t[ty + i * 8][tx] = (n < N) ? s[(size_t)k * N + n] : 0.f;
  }
  __syncthreads();
#pragma unroll
  for (int i = 0; i < 4; ++i) {
    int n = n0 + ty + i * 8;
    int k = k0 + tx;
    if (n < N) d[(size_t)n * 256 + k] = f2bf(t[tx][ty + i * 8]);
  }
}

__global__ void biascat_kernel(const float* __restrict__ ob,
                               const float* __restrict__ ab,
                               float* __restrict__ dst) {
  int l = blockIdx.x, i = threadIdx.x;
  dst[l * 96 + i] = (i < 64) ? ob[l * 64 + i] : ab[l * 32 + (i - 64)];
}

// ---------------------------------------------------------------------------
// bf16 MFMA GEMM: C[M,N] = A @ W^T + bias. A bf16 [M,256], WT bf16 [N,256].
// BM=BN=128, BK=64, 256 thr = 4 waves in 2x2; each wave 64x64 (4x4 frags).
// fp32 accumulate. ACT: ReLU. CBF: bf16 C, else fp32. LDS rows 72 shorts.
// ---------------------------------------------------------------------------
template <int ACT, int CBF>
__global__ __launch_bounds__(256) void mfma_gemm(
    const short* __restrict__ A, const short* __restrict__ WT,
    const float* __restrict__ bias, float* __restrict__ Cf,
    short* __restrict__ Cb, int M, int N) {
  __shared__ short As[128 * 72];
  __shared__ short Bs[128 * 72];
  int tid = threadIdx.x;
  int wave = tid >> 6, lane = tid & 63;
  int lr = lane & 15, kb = lane >> 4;
  int wr = wave >> 1, wc = wave & 1;
  int bm = blockIdx.y * 128, bn = blockIdx.x * 128;

  int srow = tid >> 1;            // 0..127
  int skh = (tid & 1) * 32;       // 0 or 32 (shorts)
  const short* aptr = A + (size_t)(bm + srow) * 256 + skh;
  const short* bptr = WT + (size_t)(bn + srow) * 256 + skh;
  short* asd = &As[srow * 72 + skh];
  short* bsd = &Bs[srow * 72 + skh];

  f32x4 acc[4][4] = {};

  for (int k0 = 0; k0 < 256; k0 += 64) {
#pragma unroll
    for (int j = 0; j < 4; ++j) {
      *reinterpret_cast<short8v*>(asd + j * 8) =
          *reinterpret_cast<const short8v*>(aptr + k0 + j * 8);
      *reinterpret_cast<short8v*>(bsd + j * 8) =
          *reinterpret_cast<const short8v*>(bptr + k0 + j * 8);
    }
    __syncthreads();
#pragma unroll
    for (int ks = 0; ks < 2; ++ks) {
      short8v af[4], bf[4];
#pragma unroll
      for (int i = 0; i < 4; ++i) {
        af[i] = *reinterpret_cast<const short8v*>(
            &As[(wr * 64 + i * 16 + lr) * 72 + ks * 32 + kb * 8]);
        bf[i] = *reinterpret_cast<const short8v*>(
            &Bs[(wc * 64 + i * 16 + lr) * 72 + ks * 32 + kb * 8]);
      }
#pragma unroll
      for (int i = 0; i < 4; ++i)
#pragma unroll
        for (int j = 0; j < 4; ++j)
          acc[i][j] = __builtin_amdgcn_mfma_f32_16x16x32_bf16(af[i], bf[j],
                                                              acc[i][j], 0, 0, 0);
    }
    __syncthreads();
  }

#pragma unroll
  for (int fn = 0; fn < 4; ++fn) {
    int c = bn + wc * 64 + fn * 16 + lr;
    if (c >= N) continue;
    float bv = bias[c];
#pragma unroll
    for (int fm = 0; fm < 4; ++fm) {
#pragma unroll
      for (int i = 0; i < 4; ++i) {
        int r = bm + wr * 64 + fm * 16 + kb * 4 + i;
        if (r < M) {
          float v = acc[fm][fn][i] + bv;
          if (ACT) v = fmaxf(v, 0.f);
          if (CBF) Cb[(size_t)r * N + c] = f2bf(v);
          else Cf[(size_t)r * N + c] = v;
        }
      }
    }
  }
}

// ---------------------------------------------------------------------------
// Deformable sampling + fused softmax, bf16 value/attn.
// 256 thr = 8 tokens x 32 lanes; lane: head = lane>>2, d8 = (lane&3)*8.
// Bijective XCD swizzle over 2500 blocks (q=312, r=4).
// ---------------------------------------------------------------------------
__global__ __launch_bounds__(256) void sample_kernel(
    const short* __restrict__ value, const float* __restrict__ offaw,
    short* __restrict__ attn) {
  __shared__ float loff[8][64];
  __shared__ float lw[8][32];
  int bid = blockIdx.x;
  int xcd = bid & 7, idx = bid >> 3;
  int swz = (xcd < 4 ? xcd * 313 : 4 * 313 + (xcd - 4) * 312) + idx;
  int tok0 = swz * 8;
  int tid = threadIdx.x;
  for (int i = tid; i < 768; i += 256) {
    int t = i / 96, j = i - t * 96;
    float v = offaw[(size_t)(tok0 + t) * 96 + j];
    if (j < 64) loff[t][j] = v; else lw[t][j - 64] = v;
  }
  __syncthreads();
  if (tid < 64) {                                   // softmax over 4 points
    int t = tid >> 3, h = tid & 7;
    float* w = &lw[t][h * 4];
    float m = fmaxf(fmaxf(w[0], w[1]), fmaxf(w[2], w[3]));
    float e0 = __expf(w[0] - m), e1 = __expf(w[1] - m);
    float e2 = __expf(w[2] - m), e3 = __expf(w[3] - m);
    float inv = 1.f / (e0 + e1 + e2 + e3);
    w[0] = e0 * inv; w[1] = e1 * inv; w[2] = e2 * inv; w[3] = e3 * inv;
  }
  __syncthreads();

  int ts = tid >> 5, lane = tid & 31;
  int token = tok0 + ts;
  int h = lane >> 2, d8 = (lane & 3) * 8;
  int b = token / S_TOK;
  int s = token - b * S_TOK;
  int ix = s % WID, iy = s / WID;
  const short* vbase = value + ((size_t)b * S_TOK) * D_MODEL + h * DH + d8;

  float acc[8] = {};
#pragma unroll
  for (int p = 0; p < N_POINTS; ++p) {
    float ox = loff[ts][h * 8 + p * 2 + 0];
    float oy = loff[ts][h * 8 + p * 2 + 1];
    float aw = lw[ts][h * 4 + p];
    float px = (float)ix + ox;
    float py = (float)iy + oy;
    float x0f = floorf(px), y0f = floorf(py);
    int x0 = (int)x0f, y0 = (int)y0f;
    float wx1 = px - x0f, wx0 = 1.f - wx1;
    float wy1 = py - y0f, wy0 = 1.f - wy1;
    float sv[8] = {};
    bool xa = (x0 >= 0) & (x0 < WID), xb = (x0 + 1 >= 0) & (x0 + 1 < WID);
    bool ya = (y0 >= 0) & (y0 < HGT), yb = (y0 + 1 >= 0) & (y0 + 1 < HGT);
#define CORNER(XOK, YOK, XI, YI, WGT)                                        \
    if ((XOK) & (YOK)) {                                                     \
      short8v v = *reinterpret_cast<const short8v*>(                         \
          vbase + (size_t)((YI) * WID + (XI)) * D_MODEL);                    \
      float wg = (WGT);                                                      \
      _Pragma("unroll")                                                      \
      for (int j = 0; j < 8; ++j) sv[j] = fmaf(wg, bf2f(v[j]), sv[j]);       \
    }
    CORNER(xa, ya, x0, y0, wx0 * wy0)
    CORNER(xb, ya, x0 + 1, y0, wx1 * wy0)
    CORNER(xa, yb, x0, y0 + 1, wx0 * wy1)
    CORNER(xb, yb, x0 + 1, y0 + 1, wx1 * wy1)
#undef CORNER
#pragma unroll
    for (int j = 0; j < 8; ++j) acc[j] = fmaf(aw, sv[j], acc[j]);
  }
  short8v o;
#pragma unroll
  for (int j = 0; j < 8; ++j) o[j] = f2bf(acc[j]);
  *reinterpret_cast<short8v*>(attn + (size_t)token * D_MODEL + h * DH + d8) = o;
}

// ---------------------------------------------------------------------------
// LayerNorm(x + add) * g + b. One wave per row, 4 rows/block (M exact).
// MODE 0: write outf (fp32) + outb (bf16).
// MODE 1: + outq = bf16(out + posb)   (for next layer's q)
// MODE 2: write outf only (final output).
// ---------------------------------------------------------------------------
template <int MODE>
__global__ __launch_bounds__(256) void ln_kernel(
    const float* __restrict__ x, const float* __restrict__ add,
    const float* __restrict__ g, const float* __restrict__ b,
    float* __restrict__ outf, short* __restrict__ outb,
    short* __restrict__ outq, const short* __restrict__ posb) {
  int row = blockIdx.x * 4 + (threadIdx.x >> 6);
  int lane = threadIdx.x & 63;
  size_t base = (size_t)row * 256 + lane * 4;
  float4 xv = *reinterpret_cast<const float4*>(x + base);
  float4 av = *reinterpret_cast<const float4*>(add + base);
  float v0 = xv.x + av.x, v1 = xv.y + av.y, v2 = xv.z + av.z, v3 = xv.w + av.w;
  float sum = v0 + v1 + v2 + v3;
  float sq = v0 * v0 + v1 * v1 + v2 * v2 + v3 * v3;
#pragma unroll
  for (int o = 32; o; o >>= 1) {
    sum += __shfl_xor(sum, o);
    sq += __shfl_xor(sq, o);
  }
  float mean = sum * (1.f / 256.f);
  float var = sq * (1.f / 256.f) - mean * mean;
  float rs = rsqrtf(var + 1e-5f);
  float4 gv = *reinterpret_cast<const float4*>(g + lane * 4);
  float4 bv = *reinterpret_cast<const float4*>(b + lane * 4);
  float4 o;
  o.x = (v0 - mean) * rs * gv.x + bv.x;
  o.y = (v1 - mean) * rs * gv.y + bv.y;
  o.z = (v2 - mean) * rs * gv.z + bv.z;
  o.w = (v3 - mean) * rs * gv.w + bv.w;
  *reinterpret_cast<float4*>(outf + base) = o;
  if (MODE == 2) return;
  short4v ob;
  ob[0] = f2bf(o.x); ob[1] = f2bf(o.y); ob[2] = f2bf(o.z); ob[3] = f2bf(o.w);
  *reinterpret_cast<short4v*>(outb + base) = ob;
  if (MODE == 1) {
    short4v p = *reinterpret_cast<const short4v*>(posb + base);
    short4v q;
    q[0] = f2bf(o.x + bf2f(p[0])); q[1] = f2bf(o.y + bf2f(p[1]));
    q[2] = f2bf(o.z + bf2f(p[2])); q[3] = f2bf(o.w + bf2f(p[3]));
    *reinterpret_cast<short4v*>(outq + base) = q;
  }
}

// ---------------------------------------------------------------------------
extern "C" void kernel_launch(void* const* d_in, const int* in_sizes, int n_in,
                              void* d_out, int out_size, void* d_ws,
                              size_t ws_size, hipStream_t stream) {
  const float* features  = (const float*)d_in[0];
  const float* pos_embed = (const float*)d_in[1];
  const float* level_emb = (const float*)d_in[2];
  const float* off_w = (const float*)d_in[3];
  const float* off_b = (const float*)d_in[4];
  const float* aw_w  = (const float*)d_in[5];
  const float* aw_b  = (const float*)d_in[6];
  const float* val_w = (const float*)d_in[7];
  const float* val_b = (const float*)d_in[8];
  const float* out_w = (const float*)d_in[9];
  const float* out_b = (const float*)d_in[10];
  const float* ln1_g = (const float*)d_in[11];
  const float* ln1_b = (const float*)d_in[12];
  const float* ffn_w1 = (const float*)d_in[13];
  const float* ffn_b1 = (const float*)d_in[14];
  const float* ffn_w2 = (const float*)d_in[15];
  const float* ffn_b2 = (const float*)d_in[16];
  const float* ln3_g = (const float*)d_in[17];
  const float* ln3_b = (const float*)d_in[18];

  float* ws = (float*)d_ws;
  const size_t BIG = (size_t)M_TOK * D_MODEL;  // 5.12M elems
  float* src   = ws;                           // [M,256] f32
  float* offaw = src + BIG;                    // [M,96]  f32
  short* posb  = (short*)(offaw + (size_t)M_TOK * 96);  // [M,256] bf16
  short* srcb  = posb + BIG;                   // [M,256] bf16
  short* qb    = srcb + BIG;                   // [M,256] bf16
  short* value = qb + BIG;                     // [M,256] bf16; reused as hidden
  short* attn  = value + BIG;                  // [M,256] bf16
  short* wv  = attn + BIG;                     // [6][256][256] bf16 (W^T)
  short* wo  = wv + (size_t)6 * 65536;
  short* w1t = wo + (size_t)6 * 65536;
  short* w2t = w1t + (size_t)6 * 65536;
  short* woa = w2t + (size_t)6 * 65536;        // [6][96][256] bf16
  float* bias96 = (float*)(woa + (size_t)6 * 96 * 256);  // [6][96]
  float* tmp = (float*)d_out;                  // [M,256] f32 scratch

  transpose_kernel<<<dim3(313, 8, 4), dim3(32, 8), 0, stream>>>(
      features, pos_embed, level_emb, src, posb);
  convT_kernel<<<dim3(8, 8, 6), dim3(32, 8), 0, stream>>>(val_w, wv, 256,
                                                          65536, 65536);
  convT_kernel<<<dim3(8, 8, 6), dim3(32, 8), 0, stream>>>(out_w, wo, 256,
                                                          65536, 65536);
  convT_kernel<<<dim3(8, 8, 6), dim3(32, 8), 0, stream>>>(ffn_w1, w1t, 256,
                                                          65536, 65536);
  convT_kernel<<<dim3(8, 8, 6), dim3(32, 8), 0, stream>>>(ffn_w2, w2t, 256,
                                                          65536, 65536);
  convT_kernel<<<dim3(2, 8, 6), dim3(32, 8), 0, stream>>>(
      off_w, woa, 64, (size_t)256 * 64, (size_t)96 * 256);
  convT_kernel<<<dim3(1, 8, 6), dim3(32, 8), 0, stream>>>(
      aw_w, woa + (size_t)64 * 256, 32, (size_t)256 * 32, (size_t)96 * 256);
  biascat_kernel<<<dim3(6), dim3(96), 0, stream>>>(off_b, aw_b, bias96);
  pack_kernel<<<dim3(5000), 256, 0, stream>>>(src, posb, srcb, qb);

  for (int l = 0; l < N_LAYERS; ++l) {
    const short* wvl = wv + (size_t)l * 65536;
    const short* wol = wo + (size_t)l * 65536;
    const short* w1l = w1t + (size_t)l * 65536;
    const short* w2l = w2t + (size_t)l * 65536;
    const short* woal = woa + (size_t)l * 96 * 256;

    mfma_gemm<0, 1><<<dim3(2, 157), 256, 0, stream>>>(
        srcb, wvl, val_b + (size_t)l * 256, nullptr, value, M_TOK, 256);
    mfma_gemm<0, 0><<<dim3(1, 157), 256, 0, stream>>>(
        qb, woal, bias96 + (size_t)l * 96, offaw, nullptr, M_TOK, 96);
    sample_kernel<<<dim3(M_TOK / 8), 256, 0, stream>>>(value, offaw, attn);
    mfma_gemm<0, 0><<<dim3(2, 157), 256, 0, stream>>>(
        attn, wol, out_b + (size_t)l * 256, tmp, nullptr, M_TOK, 256);
    ln_kernel<0><<<dim3(5000), 256, 0, stream>>>(
        src, tmp, ln1_g + l * 256, ln1_b + l * 256, src, srcb, nullptr, nullptr);
    mfma_gemm<1, 1><<<dim3(2, 157), 256, 0, stream>>>(
        srcb, w1l, ffn_b1 + (size_t)l * 256, nullptr, value, M_TOK, 256);
    mfma_gemm<0, 0><<<dim3(2, 157), 256, 0, stream>>>(
        value, w2l, ffn_b2 + (size_t)l * 256, tmp, nullptr, M_TOK, 256);
    if (l == N_LAYERS - 1) {
      ln_kernel<2><<<dim3(5000), 256, 0, stream>>>(
          src, tmp, ln3_g + l * 256, ln3_b + l * 256, (float*)d_out, nullptr,
          nullptr, nullptr);
    } else {
      ln_kernel<1><<<dim3(5000), 256, 0, stream>>>(
          src, tmp, ln3_g + l * 256, ln3_b + l * 256, src, srcb, qb, posb);
    }
  }
}

// Round 5
// 798.588 us; speedup vs baseline: 2.2636x; 1.0561x over previous
//
#include <hip/hip_runtime.h>
#include <math.h>

#define HGT 100
#define WID 100
#define S_TOK (HGT * WID)          // 10000
#define D_MODEL 256
#define N_HEADS 8
#define DH 32
#define N_POINTS 4
#define N_LAYERS 6
#define BS 2
#define M_TOK (BS * S_TOK)         // 20000

typedef __attribute__((ext_vector_type(8))) short short8v;   // 8 bf16 = 16 B
typedef __attribute__((ext_vector_type(4))) short short4v;   // 4 bf16 = 8 B
typedef __attribute__((ext_vector_type(4))) float f32x4;

__device__ __forceinline__ short f2bf(float f) {
  union { float f; unsigned u; } v; v.f = f;
  unsigned r = v.u + 0x7fff + ((v.u >> 16) & 1);   // round-to-nearest-even
  return (short)(r >> 16);
}
__device__ __forceinline__ float bf2f(short s) {
  union { unsigned u; float f; } v;
  v.u = ((unsigned)(unsigned short)s) << 16;
  return v.f;
}

// ---------------------------------------------------------------------------
// Transpose [bs, C, S] -> [bs, S, C]. z: 0,1 = features b (fp32 out src);
// 2,3 = pos b (bf16 out posb, + level_embed).
// ---------------------------------------------------------------------------
__global__ __launch_bounds__(256) void transpose_kernel(
    const float* __restrict__ feat, const float* __restrict__ posin,
    const float* __restrict__ level, float* __restrict__ src,
    short* __restrict__ posb) {
  __shared__ float tile[32][33];
  int which = blockIdx.z;
  int b = which & 1;
  int tsel = which >> 1;
  const float* in = tsel ? posin : feat;
  int s0 = blockIdx.x * 32;
  int c0 = blockIdx.y * 32;
  int tx = threadIdx.x, ty = threadIdx.y;
#pragma unroll
  for (int i = 0; i < 4; ++i) {
    int c = c0 + ty + i * 8;
    int s = s0 + tx;
    float v = (s < S_TOK) ? in[((size_t)b * D_MODEL + c) * S_TOK + s] : 0.f;
    tile[ty + i * 8][tx] = v;
  }
  __syncthreads();
#pragma unroll
  for (int i = 0; i < 4; ++i) {
    int s = s0 + ty + i * 8;
    int c = c0 + tx;
    if (s < S_TOK) {
      float v = tile[tx][ty + i * 8];
      size_t o = ((size_t)b * S_TOK + s) * D_MODEL + c;
      if (tsel) posb[o] = f2bf(v + level[c]);
      else src[o] = v;
    }
  }
}

// srcb = bf16(src); qb = bf16(src + posb). 4 elems/thread, grid 5000.
__global__ __launch_bounds__(256) void pack_kernel(
    const float* __restrict__ src, const short* __restrict__ posb,
    short* __restrict__ srcb, short* __restrict__ qb) {
  int i = (blockIdx.x * 256 + threadIdx.x) * 4;
  float4 s = *reinterpret_cast<const float4*>(src + i);
  short4v p = *reinterpret_cast<const short4v*>(posb + i);
  short4v sb, q;
  sb[0] = f2bf(s.x); sb[1] = f2bf(s.y); sb[2] = f2bf(s.z); sb[3] = f2bf(s.w);
  q[0] = f2bf(s.x + bf2f(p[0])); q[1] = f2bf(s.y + bf2f(p[1]));
  q[2] = f2bf(s.z + bf2f(p[2])); q[3] = f2bf(s.w + bf2f(p[3]));
  *reinterpret_cast<short4v*>(srcb + i) = sb;
  *reinterpret_cast<short4v*>(qb + i) = q;
}

// ---------------------------------------------------------------------------
// Weight transpose + fp32->bf16: src [L][K=256][N] -> dst [L][N][256] bf16.
// ---------------------------------------------------------------------------
__global__ __launch_bounds__(256) void convT_kernel(
    const float* __restrict__ src, short* __restrict__ dst, int N,
    size_t srcLS, size_t dstLS) {
  __shared__ float t[32][33];
  int l = blockIdx.z;
  const float* s = src + (size_t)l * srcLS;
  short* d = dst + (size_t)l * dstLS;
  int n0 = blockIdx.x * 32, k0 = blockIdx.y * 32;
  int tx = threadIdx.x, ty = threadIdx.y;
#pragma unroll
  for (int i = 0; i < 4; ++i) {
    int k = k0 + ty + i * 8;
    int n = n0 + tx;
    t[ty + i * 8][tx] = (n < N) ? s[(size_t)k * N + n] : 0.f;
  }
  __syncthreads();
#pragma unroll
  for (int i = 0; i < 4; ++i) {
    int n = n0 + ty + i * 8;
    int k = k0 + tx;
    if (n < N) d[(size_t)n * 256 + k] = f2bf(t[tx][ty + i * 8]);
  }
}

__global__ void biascat_kernel(const float* __restrict__ ob,
                               const float* __restrict__ ab,
                               float* __restrict__ dst) {
  int l = blockIdx.x, i = threadIdx.x;
  dst[l * 96 + i] = (i < 64) ? ob[l * 64 + i] : ab[l * 32 + (i - 64)];
}

// ---------------------------------------------------------------------------
// Unified bf16 MFMA GEMM, BM=128, BN=N=K=256, 512 thr = 8 waves (2x4),
// wave tile 64x64 (4x4 16x16x32 frags), fp32 accumulate. Grid: 157.
// MODE 0: C = A@W^T + bias (+ReLU if ACT) -> Cb bf16.
// MODE 1: LN(srcf + C) -> srcf f32 (in-place) + srcb bf16.
// MODE 2: MODE 1 + qb = bf16(out + posb).
// MODE 3: LN(srcf + C) -> outf f32 only (final output).
// ---------------------------------------------------------------------------
template <int ACT, int MODE>
__global__ __launch_bounds__(512) void gemm_fused(
    const short* __restrict__ A, const short* __restrict__ WT,
    const float* __restrict__ bias, short* __restrict__ Cb,
    float* __restrict__ srcf, float* __restrict__ outf,
    short* __restrict__ srcb, short* __restrict__ qb,
    const short* __restrict__ posb, const float* __restrict__ g,
    const float* __restrict__ lnb) {
  __shared__ short As[128 * 72];
  __shared__ short Bs[256 * 72];
  int tid = threadIdx.x;
  int wave = tid >> 6, lane = tid & 63;
  int lr = lane & 15, kb = lane >> 4;
  int wr = wave >> 2, wc = wave & 3;
  int bm = blockIdx.x * 128;

  int arow = tid >> 2, ach = (tid & 3) * 16;   // 128 rows x 4 chunks of 16
  int brow = tid >> 1, bch = (tid & 1) * 32;   // 256 rows x 2 chunks of 32
  bool aok = (bm + arow) < M_TOK;
  const short* aptr = A + (size_t)(bm + arow) * 256 + ach;
  const short* bptr = WT + (size_t)brow * 256 + bch;
  short* asd = &As[arow * 72 + ach];
  short* bsd = &Bs[brow * 72 + bch];

  f32x4 acc[4][4] = {};

  for (int k0 = 0; k0 < 256; k0 += 64) {
    short8v a0 = {}, a1 = {};
    if (aok) {
      a0 = *reinterpret_cast<const short8v*>(aptr + k0);
      a1 = *reinterpret_cast<const short8v*>(aptr + k0 + 8);
    }
    *reinterpret_cast<short8v*>(asd) = a0;
    *reinterpret_cast<short8v*>(asd + 8) = a1;
#pragma unroll
    for (int j = 0; j < 4; ++j)
      *reinterpret_cast<short8v*>(bsd + j * 8) =
          *reinterpret_cast<const short8v*>(bptr + k0 + j * 8);
    __syncthreads();
#pragma unroll
    for (int ks = 0; ks < 2; ++ks) {
      short8v af[4], bf[4];
#pragma unroll
      for (int i = 0; i < 4; ++i) {
        af[i] = *reinterpret_cast<const short8v*>(
            &As[(wr * 64 + i * 16 + lr) * 72 + ks * 32 + kb * 8]);
        bf[i] = *reinterpret_cast<const short8v*>(
            &Bs[(wc * 64 + i * 16 + lr) * 72 + ks * 32 + kb * 8]);
      }
#pragma unroll
      for (int i = 0; i < 4; ++i)
#pragma unroll
        for (int j = 0; j < 4; ++j)
          acc[i][j] = __builtin_amdgcn_mfma_f32_16x16x32_bf16(af[i], bf[j],
                                                              acc[i][j], 0, 0, 0);
    }
    __syncthreads();
  }

  float bb[4];
#pragma unroll
  for (int fn = 0; fn < 4; ++fn) bb[fn] = bias[wc * 64 + fn * 16 + lr];

  if (MODE == 0) {
#pragma unroll
    for (int fm = 0; fm < 4; ++fm)
#pragma unroll
      for (int i = 0; i < 4; ++i) {
        int r = bm + wr * 64 + fm * 16 + kb * 4 + i;
        if (r >= M_TOK) continue;
#pragma unroll
        for (int fn = 0; fn < 4; ++fn) {
          int c = wc * 64 + fn * 16 + lr;
          float v = acc[fm][fn][i] + bb[fn];
          if (ACT) v = fmaxf(v, 0.f);
          Cb[(size_t)r * 256 + c] = f2bf(v);
        }
      }
    return;
  }

  // ---- fused residual + LayerNorm epilogue ----
  float* lns = (float*)As;           // [128][4] row partial sums
  float* lnq = lns + 512;            // [128][4] row partial sumsq
  float mean_[4][4], rs_[4][4];
#pragma unroll
  for (int fm = 0; fm < 4; ++fm)
#pragma unroll
    for (int i = 0; i < 4; ++i) {
      int lrow = wr * 64 + fm * 16 + kb * 4 + i;
      int r = bm + lrow;
      bool ok = r < M_TOK;
      float s = 0.f, q = 0.f;
#pragma unroll
      for (int fn = 0; fn < 4; ++fn) {
        int c = wc * 64 + fn * 16 + lr;
        float v = acc[fm][fn][i] + bb[fn];
        if (ok) v += srcf[(size_t)r * 256 + c];
        acc[fm][fn][i] = v;
        s += v; q += v * v;
      }
#pragma unroll
      for (int o = 1; o < 16; o <<= 1) {
        s += __shfl_xor(s, o);
        q += __shfl_xor(q, o);
      }
      if (lr == 0) { lns[lrow * 4 + wc] = s; lnq[lrow * 4 + wc] = q; }
    }
  __syncthreads();
#pragma unroll
  for (int fm = 0; fm < 4; ++fm)
#pragma unroll
    for (int i = 0; i < 4; ++i) {
      int lrow = wr * 64 + fm * 16 + kb * 4 + i;
      float S = lns[lrow * 4 + 0] + lns[lrow * 4 + 1] + lns[lrow * 4 + 2] +
                lns[lrow * 4 + 3];
      float Q = lnq[lrow * 4 + 0] + lnq[lrow * 4 + 1] + lnq[lrow * 4 + 2] +
                lnq[lrow * 4 + 3];
      float mean = S * (1.f / 256.f);
      float var = Q * (1.f / 256.f) - mean * mean;
      mean_[fm][i] = mean;
      rs_[fm][i] = rsqrtf(var + 1e-5f);
    }
  float g4[4], lb4[4];
#pragma unroll
  for (int fn = 0; fn < 4; ++fn) {
    int c = wc * 64 + fn * 16 + lr;
    g4[fn] = g[c]; lb4[fn] = lnb[c];
  }
#pragma unroll
  for (int fm = 0; fm < 4; ++fm)
#pragma unroll
    for (int i = 0; i < 4; ++i) {
      int r = bm + wr * 64 + fm * 16 + kb * 4 + i;
      if (r >= M_TOK) continue;
#pragma unroll
      for (int fn = 0; fn < 4; ++fn) {
        int c = wc * 64 + fn * 16 + lr;
        float o = (acc[fm][fn][i] - mean_[fm][i]) * rs_[fm][i] * g4[fn] + lb4[fn];
        if (MODE == 3) {
          outf[(size_t)r * 256 + c] = o;
        } else {
          srcf[(size_t)r * 256 + c] = o;
          srcb[(size_t)r * 256 + c] = f2bf(o);
          if (MODE == 2)
            qb[(size_t)r * 256 + c] = f2bf(o + bf2f(posb[(size_t)r * 256 + c]));
        }
      }
    }
}

// ---------------------------------------------------------------------------
// N=96 GEMM (offsets+attn logits): C f32 = A @ W^T + bias.
// BM=128, BN=128(>=96), BK=64, 256 thr = 2x2 waves of 64x64.
// ---------------------------------------------------------------------------
__global__ __launch_bounds__(256) void gemm96(
    const short* __restrict__ A, const short* __restrict__ WT,
    const float* __restrict__ bias, float* __restrict__ Cf) {
  const int N = 96;
  __shared__ short As[128 * 72];
  __shared__ short Bs[128 * 72];
  int tid = threadIdx.x;
  int wave = tid >> 6, lane = tid & 63;
  int lr = lane & 15, kb = lane >> 4;
  int wr = wave >> 1, wc = wave & 1;
  int bm = blockIdx.x * 128;

  int srow = tid >> 1;
  int skh = (tid & 1) * 32;
  bool aok = (bm + srow) < M_TOK;
  bool bok = srow < N;
  const short* aptr = A + (size_t)(bm + srow) * 256 + skh;
  const short* bptr = WT + (size_t)srow * 256 + skh;
  short* asd = &As[srow * 72 + skh];
  short* bsd = &Bs[srow * 72 + skh];

  f32x4 acc[4][4] = {};

  for (int k0 = 0; k0 < 256; k0 += 64) {
    short8v a0 = {}, a1 = {}, a2 = {}, a3 = {};
    if (aok) {
      a0 = *reinterpret_cast<const short8v*>(aptr + k0);
      a1 = *reinterpret_cast<const short8v*>(aptr + k0 + 8);
      a2 = *reinterpret_cast<const short8v*>(aptr + k0 + 16);
      a3 = *reinterpret_cast<const short8v*>(aptr + k0 + 24);
    }
    *reinterpret_cast<short8v*>(asd) = a0;
    *reinterpret_cast<short8v*>(asd + 8) = a1;
    *reinterpret_cast<short8v*>(asd + 16) = a2;
    *reinterpret_cast<short8v*>(asd + 24) = a3;
    short8v b0 = {}, b1 = {}, b2 = {}, b3 = {};
    if (bok) {
      b0 = *reinterpret_cast<const short8v*>(bptr + k0);
      b1 = *reinterpret_cast<const short8v*>(bptr + k0 + 8);
      b2 = *reinterpret_cast<const short8v*>(bptr + k0 + 16);
      b3 = *reinterpret_cast<const short8v*>(bptr + k0 + 24);
    }
    *reinterpret_cast<short8v*>(bsd) = b0;
    *reinterpret_cast<short8v*>(bsd + 8) = b1;
    *reinterpret_cast<short8v*>(bsd + 16) = b2;
    *reinterpret_cast<short8v*>(bsd + 24) = b3;
    __syncthreads();
#pragma unroll
    for (int ks = 0; ks < 2; ++ks) {
      short8v af[4], bf[4];
#pragma unroll
      for (int i = 0; i < 4; ++i) {
        af[i] = *reinterpret_cast<const short8v*>(
            &As[(wr * 64 + i * 16 + lr) * 72 + ks * 32 + kb * 8]);
        bf[i] = *reinterpret_cast<const short8v*>(
            &Bs[(wc * 64 + i * 16 + lr) * 72 + ks * 32 + kb * 8]);
      }
#pragma unroll
      for (int i = 0; i < 4; ++i)
#pragma unroll
        for (int j = 0; j < 4; ++j)
          acc[i][j] = __builtin_amdgcn_mfma_f32_16x16x32_bf16(af[i], bf[j],
                                                              acc[i][j], 0, 0, 0);
    }
    __syncthreads();
  }

#pragma unroll
  for (int fn = 0; fn < 4; ++fn) {
    int c = wc * 64 + fn * 16 + lr;
    if (c >= N) continue;
    float bv = bias[c];
#pragma unroll
    for (int fm = 0; fm < 4; ++fm)
#pragma unroll
      for (int i = 0; i < 4; ++i) {
        int r = bm + wr * 64 + fm * 16 + kb * 4 + i;
        if (r < M_TOK) Cf[(size_t)r * N + c] = acc[fm][fn][i] + bv;
      }
  }
}

// ---------------------------------------------------------------------------
// Deformable sampling + fused softmax, bf16 value/attn.
// 256 thr = 8 tokens x 32 lanes; lane: head = lane>>2, d8 = (lane&3)*8.
// Bijective XCD swizzle over 2500 blocks (q=312, r=4).
// ---------------------------------------------------------------------------
__global__ __launch_bounds__(256) void sample_kernel(
    const short* __restrict__ value, const float* __restrict__ offaw,
    short* __restrict__ attn) {
  __shared__ float loff[8][64];
  __shared__ float lw[8][32];
  int bid = blockIdx.x;
  int xcd = bid & 7, idx = bid >> 3;
  int swz = (xcd < 4 ? xcd * 313 : 4 * 313 + (xcd - 4) * 312) + idx;
  int tok0 = swz * 8;
  int tid = threadIdx.x;
  for (int i = tid; i < 768; i += 256) {
    int t = i / 96, j = i - t * 96;
    float v = offaw[(size_t)(tok0 + t) * 96 + j];
    if (j < 64) loff[t][j] = v; else lw[t][j - 64] = v;
  }
  __syncthreads();
  if (tid < 64) {                                   // softmax over 4 points
    int t = tid >> 3, h = tid & 7;
    float* w = &lw[t][h * 4];
    float m = fmaxf(fmaxf(w[0], w[1]), fmaxf(w[2], w[3]));
    float e0 = __expf(w[0] - m), e1 = __expf(w[1] - m);
    float e2 = __expf(w[2] - m), e3 = __expf(w[3] - m);
    float inv = 1.f / (e0 + e1 + e2 + e3);
    w[0] = e0 * inv; w[1] = e1 * inv; w[2] = e2 * inv; w[3] = e3 * inv;
  }
  __syncthreads();

  int ts = tid >> 5, lane = tid & 31;
  int token = tok0 + ts;
  int h = lane >> 2, d8 = (lane & 3) * 8;
  int b = token / S_TOK;
  int s = token - b * S_TOK;
  int ix = s % WID, iy = s / WID;
  const short* vbase = value + ((size_t)b * S_TOK) * D_MODEL + h * DH + d8;

  float acc[8] = {};
#pragma unroll
  for (int p = 0; p < N_POINTS; ++p) {
    float ox = loff[ts][h * 8 + p * 2 + 0];
    float oy = loff[ts][h * 8 + p * 2 + 1];
    float aw = lw[ts][h * 4 + p];
    float px = (float)ix + ox;
    float py = (float)iy + oy;
    float x0f = floorf(px), y0f = floorf(py);
    int x0 = (int)x0f, y0 = (int)y0f;
    float wx1 = px - x0f, wx0 = 1.f - wx1;
    float wy1 = py - y0f, wy0 = 1.f - wy1;
    float sv[8] = {};
    bool xa = (x0 >= 0) & (x0 < WID), xb = (x0 + 1 >= 0) & (x0 + 1 < WID);
    bool ya = (y0 >= 0) & (y0 < HGT), yb = (y0 + 1 >= 0) & (y0 + 1 < HGT);
#define CORNER(XOK, YOK, XI, YI, WGT)                                        \
    if ((XOK) & (YOK)) {                                                     \
      short8v v = *reinterpret_cast<const short8v*>(                         \
          vbase + (size_t)((YI) * WID + (XI)) * D_MODEL);                    \
      float wg = (WGT);                                                      \
      _Pragma("unroll")                                                      \
      for (int j = 0; j < 8; ++j) sv[j] = fmaf(wg, bf2f(v[j]), sv[j]);       \
    }
    CORNER(xa, ya, x0, y0, wx0 * wy0)
    CORNER(xb, ya, x0 + 1, y0, wx1 * wy0)
    CORNER(xa, yb, x0, y0 + 1, wx0 * wy1)
    CORNER(xb, yb, x0 + 1, y0 + 1, wx1 * wy1)
#undef CORNER
#pragma unroll
    for (int j = 0; j < 8; ++j) acc[j] = fmaf(aw, sv[j], acc[j]);
  }
  short8v o;
#pragma unroll
  for (int j = 0; j < 8; ++j) o[j] = f2bf(acc[j]);
  *reinterpret_cast<short8v*>(attn + (size_t)token * D_MODEL + h * DH + d8) = o;
}

// ---------------------------------------------------------------------------
extern "C" void kernel_launch(void* const* d_in, const int* in_sizes, int n_in,
                              void* d_out, int out_size, void* d_ws,
                              size_t ws_size, hipStream_t stream) {
  const float* features  = (const float*)d_in[0];
  const float* pos_embed = (const float*)d_in[1];
  const float* level_emb = (const float*)d_in[2];
  const float* off_w = (const float*)d_in[3];
  const float* off_b = (const float*)d_in[4];
  const float* aw_w  = (const float*)d_in[5];
  const float* aw_b  = (const float*)d_in[6];
  const float* val_w = (const float*)d_in[7];
  const float* val_b = (const float*)d_in[8];
  const float* out_w = (const float*)d_in[9];
  const float* out_b = (const float*)d_in[10];
  const float* ln1_g = (const float*)d_in[11];
  const float* ln1_b = (const float*)d_in[12];
  const float* ffn_w1 = (const float*)d_in[13];
  const float* ffn_b1 = (const float*)d_in[14];
  const float* ffn_w2 = (const float*)d_in[15];
  const float* ffn_b2 = (const float*)d_in[16];
  const float* ln3_g = (const float*)d_in[17];
  const float* ln3_b = (const float*)d_in[18];

  float* ws = (float*)d_ws;
  const size_t BIG = (size_t)M_TOK * D_MODEL;  // 5.12M elems
  float* src   = ws;                           // [M,256] f32 (residual)
  float* offaw = src + BIG;                    // [M,96]  f32
  short* posb  = (short*)(offaw + (size_t)M_TOK * 96);  // [M,256] bf16
  short* srcb  = posb + BIG;                   // [M,256] bf16
  short* qb    = srcb + BIG;                   // [M,256] bf16
  short* value = qb + BIG;                     // [M,256] bf16; reused as hidden
  short* attn  = value + BIG;                  // [M,256] bf16
  short* wv  = attn + BIG;                     // [6][256][256] bf16 (W^T)
  short* wo  = wv + (size_t)6 * 65536;
  short* w1t = wo + (size_t)6 * 65536;
  short* w2t = w1t + (size_t)6 * 65536;
  short* woa = w2t + (size_t)6 * 65536;        // [6][96][256] bf16
  float* bias96 = (float*)(woa + (size_t)6 * 96 * 256);  // [6][96]

  transpose_kernel<<<dim3(313, 8, 4), dim3(32, 8), 0, stream>>>(
      features, pos_embed, level_emb, src, posb);
  convT_kernel<<<dim3(8, 8, 6), dim3(32, 8), 0, stream>>>(val_w, wv, 256,
                                                          65536, 65536);
  convT_kernel<<<dim3(8, 8, 6), dim3(32, 8), 0, stream>>>(out_w, wo, 256,
                                                          65536, 65536);
  convT_kernel<<<dim3(8, 8, 6), dim3(32, 8), 0, stream>>>(ffn_w1, w1t, 256,
                                                          65536, 65536);
  convT_kernel<<<dim3(8, 8, 6), dim3(32, 8), 0, stream>>>(ffn_w2, w2t, 256,
                                                          65536, 65536);
  convT_kernel<<<dim3(2, 8, 6), dim3(32, 8), 0, stream>>>(
      off_w, woa, 64, (size_t)256 * 64, (size_t)96 * 256);
  convT_kernel<<<dim3(1, 8, 6), dim3(32, 8), 0, stream>>>(
      aw_w, woa + (size_t)64 * 256, 32, (size_t)256 * 32, (size_t)96 * 256);
  biascat_kernel<<<dim3(6), dim3(96), 0, stream>>>(off_b, aw_b, bias96);
  pack_kernel<<<dim3(5000), 256, 0, stream>>>(src, posb, srcb, qb);

  for (int l = 0; l < N_LAYERS; ++l) {
    const short* wvl = wv + (size_t)l * 65536;
    const short* wol = wo + (size_t)l * 65536;
    const short* w1l = w1t + (size_t)l * 65536;
    const short* w2l = w2t + (size_t)l * 65536;
    const short* woal = woa + (size_t)l * 96 * 256;

    // value projection -> value bf16
    gemm_fused<0, 0><<<157, 512, 0, stream>>>(
        srcb, wvl, val_b + (size_t)l * 256, value, nullptr, nullptr, nullptr,
        nullptr, nullptr, nullptr, nullptr);
    // offsets + attn logits -> offaw f32
    gemm96<<<157, 256, 0, stream>>>(qb, woal, bias96 + (size_t)l * 96, offaw);
    // deformable sampling -> attn bf16
    sample_kernel<<<M_TOK / 8, 256, 0, stream>>>(value, offaw, attn);
    // out-proj + residual + LN1 -> src f32, srcb bf16
    gemm_fused<0, 1><<<157, 512, 0, stream>>>(
        attn, wol, out_b + (size_t)l * 256, nullptr, src, nullptr, srcb,
        nullptr, nullptr, ln1_g + l * 256, ln1_b + l * 256);
    // FFN1 + ReLU -> hidden bf16 (reuse value buffer)
    gemm_fused<1, 0><<<157, 512, 0, stream>>>(
        srcb, w1l, ffn_b1 + (size_t)l * 256, value, nullptr, nullptr, nullptr,
        nullptr, nullptr, nullptr, nullptr);
    // FFN2 + residual + LN3 -> src/srcb/qb  (last layer: d_out f32 only)
    if (l == N_LAYERS - 1) {
      gemm_fused<0, 3><<<157, 512, 0, stream>>>(
          value, w2l, ffn_b2 + (size_t)l * 256, nullptr, src, (float*)d_out,
          nullptr, nullptr, nullptr, ln3_g + l * 256, ln3_b + l * 256);
    } else {
      gemm_fused<0, 2><<<157, 512, 0, stream>>>(
          value, w2l, ffn_b2 + (size_t)l * 256, nullptr, src, nullptr, srcb,
          qb, posb, ln3_g + l * 256, ln3_b + l * 256);
    }
  }
}

// Round 6
// 635.380 us; speedup vs baseline: 2.8450x; 1.2569x over previous
//
#include <hip/hip_runtime.h>
#include <math.h>

#define HGT 100
#define WID 100
#define S_TOK (HGT * WID)          // 10000
#define D_MODEL 256
#define N_HEADS 8
#define DH 32
#define N_POINTS 4
#define N_LAYERS 6
#define BS 2
#define M_TOK (BS * S_TOK)         // 20000

typedef __attribute__((ext_vector_type(8))) short short8v;   // 8 bf16 = 16 B
typedef __attribute__((ext_vector_type(4))) short short4v;   // 4 bf16 = 8 B
typedef __attribute__((ext_vector_type(4))) float f32x4;

__device__ __forceinline__ short f2bf(float f) {
  union { float f; unsigned u; } v; v.f = f;
  unsigned r = v.u + 0x7fff + ((v.u >> 16) & 1);   // round-to-nearest-even
  return (short)(r >> 16);
}
__device__ __forceinline__ float bf2f(short s) {
  union { unsigned u; float f; } v;
  v.u = ((unsigned)(unsigned short)s) << 16;
  return v.f;
}

// ---------------------------------------------------------------------------
// Transpose [bs, C, S] -> [bs, S, C]. z: 0,1 = features b (fp32 out src);
// 2,3 = pos b (bf16 out posb, + level_embed).
// ---------------------------------------------------------------------------
__global__ __launch_bounds__(256) void transpose_kernel(
    const float* __restrict__ feat, const float* __restrict__ posin,
    const float* __restrict__ level, float* __restrict__ src,
    short* __restrict__ posb) {
  __shared__ float tile[32][33];
  int which = blockIdx.z;
  int b = which & 1;
  int tsel = which >> 1;
  const float* in = tsel ? posin : feat;
  int s0 = blockIdx.x * 32;
  int c0 = blockIdx.y * 32;
  int tx = threadIdx.x, ty = threadIdx.y;
#pragma unroll
  for (int i = 0; i < 4; ++i) {
    int c = c0 + ty + i * 8;
    int s = s0 + tx;
    float v = (s < S_TOK) ? in[((size_t)b * D_MODEL + c) * S_TOK + s] : 0.f;
    tile[ty + i * 8][tx] = v;
  }
  __syncthreads();
#pragma unroll
  for (int i = 0; i < 4; ++i) {
    int s = s0 + ty + i * 8;
    int c = c0 + tx;
    if (s < S_TOK) {
      float v = tile[tx][ty + i * 8];
      size_t o = ((size_t)b * S_TOK + s) * D_MODEL + c;
      if (tsel) posb[o] = f2bf(v + level[c]);
      else src[o] = v;
    }
  }
}

// srcb = bf16(src); qb = bf16(src + posb). 4 elems/thread, grid 5000.
__global__ __launch_bounds__(256) void pack_kernel(
    const float* __restrict__ src, const short* __restrict__ posb,
    short* __restrict__ srcb, short* __restrict__ qb) {
  int i = (blockIdx.x * 256 + threadIdx.x) * 4;
  float4 s = *reinterpret_cast<const float4*>(src + i);
  short4v p = *reinterpret_cast<const short4v*>(posb + i);
  short4v sb, q;
  sb[0] = f2bf(s.x); sb[1] = f2bf(s.y); sb[2] = f2bf(s.z); sb[3] = f2bf(s.w);
  q[0] = f2bf(s.x + bf2f(p[0])); q[1] = f2bf(s.y + bf2f(p[1]));
  q[2] = f2bf(s.z + bf2f(p[2])); q[3] = f2bf(s.w + bf2f(p[3]));
  *reinterpret_cast<short4v*>(srcb + i) = sb;
  *reinterpret_cast<short4v*>(qb + i) = q;
}

// ---------------------------------------------------------------------------
// Weight transpose + fp32->bf16: src [L][K=256][N] -> dst [L][N][256] bf16.
// ---------------------------------------------------------------------------
__global__ __launch_bounds__(256) void convT_kernel(
    const float* __restrict__ src, short* __restrict__ dst, int N,
    size_t srcLS, size_t dstLS) {
  __shared__ float t[32][33];
  int l = blockIdx.z;
  const float* s = src + (size_t)l * srcLS;
  short* d = dst + (size_t)l * dstLS;
  int n0 = blockIdx.x * 32, k0 = blockIdx.y * 32;
  int tx = threadIdx.x, ty = threadIdx.y;
#pragma unroll
  for (int i = 0; i < 4; ++i) {
    int k = k0 + ty + i * 8;
    int n = n0 + tx;
    t[ty + i * 8][tx] = (n < N) ? s[(size_t)k * N + n] : 0.f;
  }
  __syncthreads();
#pragma unroll
  for (int i = 0; i < 4; ++i) {
    int n = n0 + ty + i * 8;
    int k = k0 + tx;
    if (n < N) d[(size_t)n * 256 + k] = f2bf(t[tx][ty + i * 8]);
  }
}

__global__ void biascat_kernel(const float* __restrict__ ob,
                               const float* __restrict__ ab,
                               float* __restrict__ dst) {
  int l = blockIdx.x, i = threadIdx.x;
  dst[l * 96 + i] = (i < 64) ? ob[l * 64 + i] : ab[l * 32 + (i - 64)];
}

// ---------------------------------------------------------------------------
// Unified bf16 MFMA GEMM, BM=64, BN=N=K=256, 512 thr = 8 waves (2x4),
// wave tile 32x64 (2x4 16x16x32 frags), fp32 accumulate. Grid: 313.
// MODE 0: C = A@W^T + bias (+ReLU if ACT) -> Cb bf16.
// MODE 1: LN(srcf + C) -> srcf f32 (in-place) + srcb bf16.
// MODE 2: MODE 1 + qb = bf16(out + posb).
// MODE 3: LN(srcf + C) -> outf f32 only (final output).
// ---------------------------------------------------------------------------
template <int ACT, int MODE>
__global__ __launch_bounds__(512) void gemm_fused(
    const short* __restrict__ A, const short* __restrict__ WT,
    const float* __restrict__ bias, short* __restrict__ Cb,
    float* __restrict__ srcf, float* __restrict__ outf,
    short* __restrict__ srcb, short* __restrict__ qb,
    const short* __restrict__ posb, const float* __restrict__ g,
    const float* __restrict__ lnb) {
  __shared__ short As[64 * 72];
  __shared__ short Bs[256 * 72];
  int tid = threadIdx.x;
  int wave = tid >> 6, lane = tid & 63;
  int lr = lane & 15, kb = lane >> 4;
  int wr = wave >> 2, wc = wave & 3;     // 2 x 4 waves
  int bm = blockIdx.x * 64;

  int arow = tid >> 3, ach = (tid & 7) * 8;    // 64 rows x 8 chunks of 8
  int brow = tid >> 1, bch = (tid & 1) * 32;   // 256 rows x 2 chunks of 32
  bool aok = (bm + arow) < M_TOK;
  const short* aptr = A + (size_t)(bm + arow) * 256 + ach;
  const short* bptr = WT + (size_t)brow * 256 + bch;
  short* asd = &As[arow * 72 + ach];
  short* bsd = &Bs[brow * 72 + bch];

  f32x4 acc[2][4] = {};

  for (int k0 = 0; k0 < 256; k0 += 64) {
    short8v a0 = {};
    if (aok) a0 = *reinterpret_cast<const short8v*>(aptr + k0);
    *reinterpret_cast<short8v*>(asd) = a0;
#pragma unroll
    for (int j = 0; j < 4; ++j)
      *reinterpret_cast<short8v*>(bsd + j * 8) =
          *reinterpret_cast<const short8v*>(bptr + k0 + j * 8);
    __syncthreads();
#pragma unroll
    for (int ks = 0; ks < 2; ++ks) {
      short8v af[2], bf[4];
#pragma unroll
      for (int i = 0; i < 2; ++i)
        af[i] = *reinterpret_cast<const short8v*>(
            &As[(wr * 32 + i * 16 + lr) * 72 + ks * 32 + kb * 8]);
#pragma unroll
      for (int j = 0; j < 4; ++j)
        bf[j] = *reinterpret_cast<const short8v*>(
            &Bs[(wc * 64 + j * 16 + lr) * 72 + ks * 32 + kb * 8]);
#pragma unroll
      for (int i = 0; i < 2; ++i)
#pragma unroll
        for (int j = 0; j < 4; ++j)
          acc[i][j] = __builtin_amdgcn_mfma_f32_16x16x32_bf16(af[i], bf[j],
                                                              acc[i][j], 0, 0, 0);
    }
    __syncthreads();
  }

  float bb[4];
#pragma unroll
  for (int fn = 0; fn < 4; ++fn) bb[fn] = bias[wc * 64 + fn * 16 + lr];

  if (MODE == 0) {
#pragma unroll
    for (int fm = 0; fm < 2; ++fm)
#pragma unroll
      for (int i = 0; i < 4; ++i) {
        int r = bm + wr * 32 + fm * 16 + kb * 4 + i;
        if (r >= M_TOK) continue;
#pragma unroll
        for (int fn = 0; fn < 4; ++fn) {
          int c = wc * 64 + fn * 16 + lr;
          float v = acc[fm][fn][i] + bb[fn];
          if (ACT) v = fmaxf(v, 0.f);
          Cb[(size_t)r * 256 + c] = f2bf(v);
        }
      }
    return;
  }

  // ---- fused residual + LayerNorm epilogue ----
  float* lns = (float*)As;           // [64][4] row partial sums
  float* lnq = lns + 256;            // [64][4] row partial sumsq
  float mean_[2][4], rs_[2][4];
#pragma unroll
  for (int fm = 0; fm < 2; ++fm)
#pragma unroll
    for (int i = 0; i < 4; ++i) {
      int lrow = wr * 32 + fm * 16 + kb * 4 + i;
      int r = bm + lrow;
      bool ok = r < M_TOK;
      float s = 0.f, q = 0.f;
#pragma unroll
      for (int fn = 0; fn < 4; ++fn) {
        int c = wc * 64 + fn * 16 + lr;
        float v = acc[fm][fn][i] + bb[fn];
        if (ok) v += srcf[(size_t)r * 256 + c];
        acc[fm][fn][i] = v;
        s += v; q += v * v;
      }
#pragma unroll
      for (int o = 1; o < 16; o <<= 1) {
        s += __shfl_xor(s, o);
        q += __shfl_xor(q, o);
      }
      if (lr == 0) { lns[lrow * 4 + wc] = s; lnq[lrow * 4 + wc] = q; }
    }
  __syncthreads();
#pragma unroll
  for (int fm = 0; fm < 2; ++fm)
#pragma unroll
    for (int i = 0; i < 4; ++i) {
      int lrow = wr * 32 + fm * 16 + kb * 4 + i;
      float S = lns[lrow * 4 + 0] + lns[lrow * 4 + 1] + lns[lrow * 4 + 2] +
                lns[lrow * 4 + 3];
      float Q = lnq[lrow * 4 + 0] + lnq[lrow * 4 + 1] + lnq[lrow * 4 + 2] +
                lnq[lrow * 4 + 3];
      float mean = S * (1.f / 256.f);
      float var = Q * (1.f / 256.f) - mean * mean;
      mean_[fm][i] = mean;
      rs_[fm][i] = rsqrtf(var + 1e-5f);
    }
  float g4[4], lb4[4];
#pragma unroll
  for (int fn = 0; fn < 4; ++fn) {
    int c = wc * 64 + fn * 16 + lr;
    g4[fn] = g[c]; lb4[fn] = lnb[c];
  }
#pragma unroll
  for (int fm = 0; fm < 2; ++fm)
#pragma unroll
    for (int i = 0; i < 4; ++i) {
      int r = bm + wr * 32 + fm * 16 + kb * 4 + i;
      if (r >= M_TOK) continue;
#pragma unroll
      for (int fn = 0; fn < 4; ++fn) {
        int c = wc * 64 + fn * 16 + lr;
        float o = (acc[fm][fn][i] - mean_[fm][i]) * rs_[fm][i] * g4[fn] + lb4[fn];
        if (MODE == 3) {
          outf[(size_t)r * 256 + c] = o;
        } else {
          srcf[(size_t)r * 256 + c] = o;
          srcb[(size_t)r * 256 + c] = f2bf(o);
          if (MODE == 2)
            qb[(size_t)r * 256 + c] = f2bf(o + bf2f(posb[(size_t)r * 256 + c]));
        }
      }
    }
}

// ---------------------------------------------------------------------------
// N=96 GEMM (offsets+attn logits): C f32 = A @ W^T + bias.
// BM=64, BN=128(>=96), BK=64, 256 thr = 2x2 waves of 32x64. Grid: 313.
// ---------------------------------------------------------------------------
__global__ __launch_bounds__(256) void gemm96(
    const short* __restrict__ A, const short* __restrict__ WT,
    const float* __restrict__ bias, float* __restrict__ Cf) {
  const int N = 96;
  __shared__ short As[64 * 72];
  __shared__ short Bs[128 * 72];
  int tid = threadIdx.x;
  int wave = tid >> 6, lane = tid & 63;
  int lr = lane & 15, kb = lane >> 4;
  int wr = wave >> 1, wc = wave & 1;     // 2 x 2 waves
  int bm = blockIdx.x * 64;

  int arow = tid >> 2, ach = (tid & 3) * 16;   // 64 rows x 4 chunks of 16
  int brow = tid >> 1, bch = (tid & 1) * 32;   // 128 rows x 2 chunks of 32
  bool aok = (bm + arow) < M_TOK;
  bool bok = brow < N;
  const short* aptr = A + (size_t)(bm + arow) * 256 + ach;
  const short* bptr = WT + (size_t)brow * 256 + bch;
  short* asd = &As[arow * 72 + ach];
  short* bsd = &Bs[brow * 72 + bch];

  f32x4 acc[2][4] = {};

  for (int k0 = 0; k0 < 256; k0 += 64) {
    short8v a0 = {}, a1 = {};
    if (aok) {
      a0 = *reinterpret_cast<const short8v*>(aptr + k0);
      a1 = *reinterpret_cast<const short8v*>(aptr + k0 + 8);
    }
    *reinterpret_cast<short8v*>(asd) = a0;
    *reinterpret_cast<short8v*>(asd + 8) = a1;
    short8v b0 = {}, b1 = {}, b2 = {}, b3 = {};
    if (bok) {
      b0 = *reinterpret_cast<const short8v*>(bptr + k0);
      b1 = *reinterpret_cast<const short8v*>(bptr + k0 + 8);
      b2 = *reinterpret_cast<const short8v*>(bptr + k0 + 16);
      b3 = *reinterpret_cast<const short8v*>(bptr + k0 + 24);
    }
    *reinterpret_cast<short8v*>(bsd) = b0;
    *reinterpret_cast<short8v*>(bsd + 8) = b1;
    *reinterpret_cast<short8v*>(bsd + 16) = b2;
    *reinterpret_cast<short8v*>(bsd + 24) = b3;
    __syncthreads();
#pragma unroll
    for (int ks = 0; ks < 2; ++ks) {
      short8v af[2], bf[4];
#pragma unroll
      for (int i = 0; i < 2; ++i)
        af[i] = *reinterpret_cast<const short8v*>(
            &As[(wr * 32 + i * 16 + lr) * 72 + ks * 32 + kb * 8]);
#pragma unroll
      for (int j = 0; j < 4; ++j)
        bf[j] = *reinterpret_cast<const short8v*>(
            &Bs[(wc * 64 + j * 16 + lr) * 72 + ks * 32 + kb * 8]);
#pragma unroll
      for (int i = 0; i < 2; ++i)
#pragma unroll
        for (int j = 0; j < 4; ++j)
          acc[i][j] = __builtin_amdgcn_mfma_f32_16x16x32_bf16(af[i], bf[j],
                                                              acc[i][j], 0, 0, 0);
    }
    __syncthreads();
  }

#pragma unroll
  for (int fn = 0; fn < 4; ++fn) {
    int c = wc * 64 + fn * 16 + lr;
    if (c >= N) continue;
    float bv = bias[c];
#pragma unroll
    for (int fm = 0; fm < 2; ++fm)
#pragma unroll
      for (int i = 0; i < 4; ++i) {
        int r = bm + wr * 32 + fm * 16 + kb * 4 + i;
        if (r < M_TOK) Cf[(size_t)r * N + c] = acc[fm][fn][i] + bv;
      }
  }
}

// ---------------------------------------------------------------------------
// Deformable sampling + fused softmax, bf16 value/attn.
// 256 thr = 8 tokens x 32 lanes; lane: head = lane>>2, d8 = (lane&3)*8.
// Bijective XCD swizzle over 2500 blocks (q=312, r=4).
// ---------------------------------------------------------------------------
__global__ __launch_bounds__(256) void sample_kernel(
    const short* __restrict__ value, const float* __restrict__ offaw,
    short* __restrict__ attn) {
  __shared__ float loff[8][64];
  __shared__ float lw[8][32];
  int bid = blockIdx.x;
  int xcd = bid & 7, idx = bid >> 3;
  int swz = (xcd < 4 ? xcd * 313 : 4 * 313 + (xcd - 4) * 312) + idx;
  int tok0 = swz * 8;
  int tid = threadIdx.x;
  for (int i = tid; i < 768; i += 256) {
    int t = i / 96, j = i - t * 96;
    float v = offaw[(size_t)(tok0 + t) * 96 + j];
    if (j < 64) loff[t][j] = v; else lw[t][j - 64] = v;
  }
  __syncthreads();
  if (tid < 64) {                                   // softmax over 4 points
    int t = tid >> 3, h = tid & 7;
    float* w = &lw[t][h * 4];
    float m = fmaxf(fmaxf(w[0], w[1]), fmaxf(w[2], w[3]));
    float e0 = __expf(w[0] - m), e1 = __expf(w[1] - m);
    float e2 = __expf(w[2] - m), e3 = __expf(w[3] - m);
    float inv = 1.f / (e0 + e1 + e2 + e3);
    w[0] = e0 * inv; w[1] = e1 * inv; w[2] = e2 * inv; w[3] = e3 * inv;
  }
  __syncthreads();

  int ts = tid >> 5, lane = tid & 31;
  int token = tok0 + ts;
  int h = lane >> 2, d8 = (lane & 3) * 8;
  int b = token / S_TOK;
  int s = token - b * S_TOK;
  int ix = s % WID, iy = s / WID;
  const short* vbase = value + ((size_t)b * S_TOK) * D_MODEL + h * DH + d8;

  float acc[8] = {};
#pragma unroll
  for (int p = 0; p < N_POINTS; ++p) {
    float ox = loff[ts][h * 8 + p * 2 + 0];
    float oy = loff[ts][h * 8 + p * 2 + 1];
    float aw = lw[ts][h * 4 + p];
    float px = (float)ix + ox;
    float py = (float)iy + oy;
    float x0f = floorf(px), y0f = floorf(py);
    int x0 = (int)x0f, y0 = (int)y0f;
    float wx1 = px - x0f, wx0 = 1.f - wx1;
    float wy1 = py - y0f, wy0 = 1.f - wy1;
    float sv[8] = {};
    bool xa = (x0 >= 0) & (x0 < WID), xb = (x0 + 1 >= 0) & (x0 + 1 < WID);
    bool ya = (y0 >= 0) & (y0 < HGT), yb = (y0 + 1 >= 0) & (y0 + 1 < HGT);
#define CORNER(XOK, YOK, XI, YI, WGT)                                        \
    if ((XOK) & (YOK)) {                                                     \
      short8v v = *reinterpret_cast<const short8v*>(                         \
          vbase + (size_t)((YI) * WID + (XI)) * D_MODEL);                    \
      float wg = (WGT);                                                      \
      _Pragma("unroll")                                                      \
      for (int j = 0; j < 8; ++j) sv[j] = fmaf(wg, bf2f(v[j]), sv[j]);       \
    }
    CORNER(xa, ya, x0, y0, wx0 * wy0)
    CORNER(xb, ya, x0 + 1, y0, wx1 * wy0)
    CORNER(xa, yb, x0, y0 + 1, wx0 * wy1)
    CORNER(xb, yb, x0 + 1, y0 + 1, wx1 * wy1)
#undef CORNER
#pragma unroll
    for (int j = 0; j < 8; ++j) acc[j] = fmaf(aw, sv[j], acc[j]);
  }
  short8v o;
#pragma unroll
  for (int j = 0; j < 8; ++j) o[j] = f2bf(acc[j]);
  *reinterpret_cast<short8v*>(attn + (size_t)token * D_MODEL + h * DH + d8) = o;
}

// ---------------------------------------------------------------------------
extern "C" void kernel_launch(void* const* d_in, const int* in_sizes, int n_in,
                              void* d_out, int out_size, void* d_ws,
                              size_t ws_size, hipStream_t stream) {
  const float* features  = (const float*)d_in[0];
  const float* pos_embed = (const float*)d_in[1];
  const float* level_emb = (const float*)d_in[2];
  const float* off_w = (const float*)d_in[3];
  const float* off_b = (const float*)d_in[4];
  const float* aw_w  = (const float*)d_in[5];
  const float* aw_b  = (const float*)d_in[6];
  const float* val_w = (const float*)d_in[7];
  const float* val_b = (const float*)d_in[8];
  const float* out_w = (const float*)d_in[9];
  const float* out_b = (const float*)d_in[10];
  const float* ln1_g = (const float*)d_in[11];
  const float* ln1_b = (const float*)d_in[12];
  const float* ffn_w1 = (const float*)d_in[13];
  const float* ffn_b1 = (const float*)d_in[14];
  const float* ffn_w2 = (const float*)d_in[15];
  const float* ffn_b2 = (const float*)d_in[16];
  const float* ln3_g = (const float*)d_in[17];
  const float* ln3_b = (const float*)d_in[18];

  float* ws = (float*)d_ws;
  const size_t BIG = (size_t)M_TOK * D_MODEL;  // 5.12M elems
  float* src   = ws;                           // [M,256] f32 (residual)
  float* offaw = src + BIG;                    // [M,96]  f32
  short* posb  = (short*)(offaw + (size_t)M_TOK * 96);  // [M,256] bf16
  short* srcb  = posb + BIG;                   // [M,256] bf16
  short* qb    = srcb + BIG;                   // [M,256] bf16
  short* value = qb + BIG;                     // [M,256] bf16; reused as hidden
  short* attn  = value + BIG;                  // [M,256] bf16
  short* wv  = attn + BIG;                     // [6][256][256] bf16 (W^T)
  short* wo  = wv + (size_t)6 * 65536;
  short* w1t = wo + (size_t)6 * 65536;
  short* w2t = w1t + (size_t)6 * 65536;
  short* woa = w2t + (size_t)6 * 65536;        // [6][96][256] bf16
  float* bias96 = (float*)(woa + (size_t)6 * 96 * 256);  // [6][96]

  transpose_kernel<<<dim3(313, 8, 4), dim3(32, 8), 0, stream>>>(
      features, pos_embed, level_emb, src, posb);
  convT_kernel<<<dim3(8, 8, 6), dim3(32, 8), 0, stream>>>(val_w, wv, 256,
                                                          65536, 65536);
  convT_kernel<<<dim3(8, 8, 6), dim3(32, 8), 0, stream>>>(out_w, wo, 256,
                                                          65536, 65536);
  convT_kernel<<<dim3(8, 8, 6), dim3(32, 8), 0, stream>>>(ffn_w1, w1t, 256,
                                                          65536, 65536);
  convT_kernel<<<dim3(8, 8, 6), dim3(32, 8), 0, stream>>>(ffn_w2, w2t, 256,
                                                          65536, 65536);
  convT_kernel<<<dim3(2, 8, 6), dim3(32, 8), 0, stream>>>(
      off_w, woa, 64, (size_t)256 * 64, (size_t)96 * 256);
  convT_kernel<<<dim3(1, 8, 6), dim3(32, 8), 0, stream>>>(
      aw_w, woa + (size_t)64 * 256, 32, (size_t)256 * 32, (size_t)96 * 256);
  biascat_kernel<<<dim3(6), dim3(96), 0, stream>>>(off_b, aw_b, bias96);
  pack_kernel<<<dim3(5000), 256, 0, stream>>>(src, posb, srcb, qb);

  for (int l = 0; l < N_LAYERS; ++l) {
    const short* wvl = wv + (size_t)l * 65536;
    const short* wol = wo + (size_t)l * 65536;
    const short* w1l = w1t + (size_t)l * 65536;
    const short* w2l = w2t + (size_t)l * 65536;
    const short* woal = woa + (size_t)l * 96 * 256;

    // value projection -> value bf16
    gemm_fused<0, 0><<<313, 512, 0, stream>>>(
        srcb, wvl, val_b + (size_t)l * 256, value, nullptr, nullptr, nullptr,
        nullptr, nullptr, nullptr, nullptr);
    // offsets + attn logits -> offaw f32
    gemm96<<<313, 256, 0, stream>>>(qb, woal, bias96 + (size_t)l * 96, offaw);
    // deformable sampling -> attn bf16
    sample_kernel<<<M_TOK / 8, 256, 0, stream>>>(value, offaw, attn);
    // out-proj + residual + LN1 -> src f32, srcb bf16
    gemm_fused<0, 1><<<313, 512, 0, stream>>>(
        attn, wol, out_b + (size_t)l * 256, nullptr, src, nullptr, srcb,
        nullptr, nullptr, ln1_g + l * 256, ln1_b + l * 256);
    // FFN1 + ReLU -> hidden bf16 (reuse value buffer)
    gemm_fused<1, 0><<<313, 512, 0, stream>>>(
        srcb, w1l, ffn_b1 + (size_t)l * 256, value, nullptr, nullptr, nullptr,
        nullptr, nullptr, nullptr, nullptr);
    // FFN2 + residual + LN3 -> src/srcb/qb  (last layer: d_out f32 only)
    if (l == N_LAYERS - 1) {
      gemm_fused<0, 3><<<313, 512, 0, stream>>>(
          value, w2l, ffn_b2 + (size_t)l * 256, nullptr, src, (float*)d_out,
          nullptr, nullptr, nullptr, ln3_g + l * 256, ln3_b + l * 256);
    } else {
      gemm_fused<0, 2><<<313, 512, 0, stream>>>(
          value, w2l, ffn_b2 + (size_t)l * 256, nullptr, src, nullptr, srcb,
          qb, posb, ln3_g + l * 256, ln3_b + l * 256);
    }
  }
}

// Round 9
// 619.674 us; speedup vs baseline: 2.9171x; 1.0253x over previous
//
#include <hip/hip_runtime.h>
#include <math.h>

#define HGT 100
#define WID 100
#define S_TOK (HGT * WID)          // 10000
#define D_MODEL 256
#define N_HEADS 8
#define DH 32
#define N_POINTS 4
#define N_LAYERS 6
#define BS 2
#define M_TOK (BS * S_TOK)         // 20000

typedef __attribute__((ext_vector_type(8))) short short8v;   // 8 bf16 = 16 B
typedef __attribute__((ext_vector_type(4))) short short4v;   // 4 bf16 = 8 B
typedef __attribute__((ext_vector_type(4))) float f32x4;

__device__ __forceinline__ short f2bf(float f) {
  union { float f; unsigned u; } v; v.f = f;
  unsigned r = v.u + 0x7fff + ((v.u >> 16) & 1);   // round-to-nearest-even
  return (short)(r >> 16);
}
__device__ __forceinline__ float bf2f(short s) {
  union { unsigned u; float f; } v;
  v.u = ((unsigned)(unsigned short)s) << 16;
  return v.f;
}

// ---------------------------------------------------------------------------
// Fused token prep: transpose [bs,C,S]->[bs,S,C] for features AND pos, and
// emit src f32, posb bf16 (pos+level), srcb bf16(src), qb bf16(src+posb).
// grid (313, 8, 2) block (32,8)
// ---------------------------------------------------------------------------
__global__ __launch_bounds__(256) void prep_tokens(
    const float* __restrict__ feat, const float* __restrict__ posin,
    const float* __restrict__ level, float* __restrict__ src,
    short* __restrict__ posb, short* __restrict__ srcb,
    short* __restrict__ qb) {
  __shared__ float tf[32][33];
  __shared__ float tp[32][33];
  int b = blockIdx.z;
  int s0 = blockIdx.x * 32;
  int c0 = blockIdx.y * 32;
  int tx = threadIdx.x, ty = threadIdx.y;
#pragma unroll
  for (int i = 0; i < 4; ++i) {
    int c = c0 + ty + i * 8;
    int s = s0 + tx;
    bool ok = s < S_TOK;
    size_t o = ((size_t)b * D_MODEL + c) * S_TOK + s;
    tf[ty + i * 8][tx] = ok ? feat[o] : 0.f;
    tp[ty + i * 8][tx] = ok ? posin[o] : 0.f;
  }
  __syncthreads();
#pragma unroll
  for (int i = 0; i < 4; ++i) {
    int s = s0 + ty + i * 8;
    int c = c0 + tx;
    if (s < S_TOK) {
      float f = tf[tx][ty + i * 8];
      float p = tp[tx][ty + i * 8] + level[c];
      size_t o = ((size_t)b * S_TOK + s) * D_MODEL + c;
      short pb = f2bf(p);
      src[o] = f;
      posb[o] = pb;
      srcb[o] = f2bf(f);
      qb[o] = f2bf(f + bf2f(pb));
    }
  }
}

// ---------------------------------------------------------------------------
// Fused weight prep: transpose + fp32->bf16 for all 6 weight groups.
// grid (8, 8, 36): z = l*6 + widx. widx 0..3: 256-col weights; 4: off (64);
// 5: aw (32, dst rows offset +64 in woa).
// ---------------------------------------------------------------------------
__global__ __launch_bounds__(256) void prep_weights(
    const float* __restrict__ val_w, const float* __restrict__ out_w,
    const float* __restrict__ ffn_w1, const float* __restrict__ ffn_w2,
    const float* __restrict__ off_w, const float* __restrict__ aw_w,
    short* __restrict__ wv, short* __restrict__ wo, short* __restrict__ w1t,
    short* __restrict__ w2t, short* __restrict__ woa) {
  int z = blockIdx.z;
  int l = z / 6, widx = z - (z / 6) * 6;
  const float* s;
  short* d;
  int N;
  if (widx == 0)      { s = val_w  + (size_t)l * 65536; d = wv  + (size_t)l * 65536; N = 256; }
  else if (widx == 1) { s = out_w  + (size_t)l * 65536; d = wo  + (size_t)l * 65536; N = 256; }
  else if (widx == 2) { s = ffn_w1 + (size_t)l * 65536; d = w1t + (size_t)l * 65536; N = 256; }
  else if (widx == 3) { s = ffn_w2 + (size_t)l * 65536; d = w2t + (size_t)l * 65536; N = 256; }
  else if (widx == 4) { s = off_w + (size_t)l * 256 * 64; d = woa + (size_t)l * 96 * 256; N = 64; }
  else                { s = aw_w  + (size_t)l * 256 * 32; d = woa + (size_t)l * 96 * 256 + (size_t)64 * 256; N = 32; }
  int n0 = blockIdx.x * 32, k0 = blockIdx.y * 32;
  if (n0 >= N) return;
  __shared__ float t[32][33];
  int tx = threadIdx.x, ty = threadIdx.y;
#pragma unroll
  for (int i = 0; i < 4; ++i) {
    int k = k0 + ty + i * 8;
    int n = n0 + tx;
    t[ty + i * 8][tx] = (n < N) ? s[(size_t)k * N + n] : 0.f;
  }
  __syncthreads();
#pragma unroll
  for (int i = 0; i < 4; ++i) {
    int n = n0 + ty + i * 8;
    int k = k0 + tx;
    if (n < N) d[(size_t)n * 256 + k] = f2bf(t[tx][ty + i * 8]);
  }
}

__global__ void biascat_kernel(const float* __restrict__ ob,
                               const float* __restrict__ ab,
                               float* __restrict__ dst) {
  int l = blockIdx.x, i = threadIdx.x;
  dst[l * 96 + i] = (i < 64) ? ob[l * 64 + i] : ab[l * 32 + (i - 64)];
}

// ---------------------------------------------------------------------------
// Unified bf16 MFMA GEMM, BM=64, BN=N=K=256, 512 thr = 8 waves (2x4),
// wave tile 32x64 (2x4 16x16x32 frags), fp32 accumulate. Grid: 313.
// (R6 body — no register prefetch; R7's pipelined variant raced.)
// MODE 0: C = A@W^T + bias (+ReLU if ACT) -> Cb bf16.
// MODE 1: LN(srcf + C) -> srcf f32 (in-place) + srcb bf16.
// MODE 2: MODE 1 + qb = bf16(out + posb).
// MODE 3: LN(srcf + C) -> outf f32 only (final output).
// ---------------------------------------------------------------------------
template <int ACT, int MODE>
__global__ __launch_bounds__(512) void gemm_fused(
    const short* __restrict__ A, const short* __restrict__ WT,
    const float* __restrict__ bias, short* __restrict__ Cb,
    float* __restrict__ srcf, float* __restrict__ outf,
    short* __restrict__ srcb, short* __restrict__ qb,
    const short* __restrict__ posb, const float* __restrict__ g,
    const float* __restrict__ lnb) {
  __shared__ short As[64 * 72];
  __shared__ short Bs[256 * 72];
  int tid = threadIdx.x;
  int wave = tid >> 6, lane = tid & 63;
  int lr = lane & 15, kb = lane >> 4;
  int wr = wave >> 2, wc = wave & 3;     // 2 x 4 waves
  int bm = blockIdx.x * 64;

  int arow = tid >> 3, ach = (tid & 7) * 8;    // 64 rows x 8 chunks of 8
  int brow = tid >> 1, bch = (tid & 1) * 32;   // 256 rows x 2 chunks of 32
  bool aok = (bm + arow) < M_TOK;
  const short* aptr = A + (size_t)(bm + arow) * 256 + ach;
  const short* bptr = WT + (size_t)brow * 256 + bch;
  short* asd = &As[arow * 72 + ach];
  short* bsd = &Bs[brow * 72 + bch];

  f32x4 acc[2][4] = {};

  for (int k0 = 0; k0 < 256; k0 += 64) {
    short8v a0 = {};
    if (aok) a0 = *reinterpret_cast<const short8v*>(aptr + k0);
    *reinterpret_cast<short8v*>(asd) = a0;
#pragma unroll
    for (int j = 0; j < 4; ++j)
      *reinterpret_cast<short8v*>(bsd + j * 8) =
          *reinterpret_cast<const short8v*>(bptr + k0 + j * 8);
    __syncthreads();
#pragma unroll
    for (int ks = 0; ks < 2; ++ks) {
      short8v af[2], bf[4];
#pragma unroll
      for (int i = 0; i < 2; ++i)
        af[i] = *reinterpret_cast<const short8v*>(
            &As[(wr * 32 + i * 16 + lr) * 72 + ks * 32 + kb * 8]);
#pragma unroll
      for (int j = 0; j < 4; ++j)
        bf[j] = *reinterpret_cast<const short8v*>(
            &Bs[(wc * 64 + j * 16 + lr) * 72 + ks * 32 + kb * 8]);
#pragma unroll
      for (int i = 0; i < 2; ++i)
#pragma unroll
        for (int j = 0; j < 4; ++j)
          acc[i][j] = __builtin_amdgcn_mfma_f32_16x16x32_bf16(af[i], bf[j],
                                                              acc[i][j], 0, 0, 0);
    }
    __syncthreads();
  }

  float bb[4];
#pragma unroll
  for (int fn = 0; fn < 4; ++fn) bb[fn] = bias[wc * 64 + fn * 16 + lr];

  if (MODE == 0) {
#pragma unroll
    for (int fm = 0; fm < 2; ++fm)
#pragma unroll
      for (int i = 0; i < 4; ++i) {
        int r = bm + wr * 32 + fm * 16 + kb * 4 + i;
        if (r >= M_TOK) continue;
#pragma unroll
        for (int fn = 0; fn < 4; ++fn) {
          int c = wc * 64 + fn * 16 + lr;
          float v = acc[fm][fn][i] + bb[fn];
          if (ACT) v = fmaxf(v, 0.f);
          Cb[(size_t)r * 256 + c] = f2bf(v);
        }
      }
    return;
  }

  // ---- fused residual + LayerNorm epilogue ----
  float* lns = (float*)As;           // [64][4] row partial sums
  float* lnq = lns + 256;            // [64][4] row partial sumsq
  float mean_[2][4], rs_[2][4];
#pragma unroll
  for (int fm = 0; fm < 2; ++fm)
#pragma unroll
    for (int i = 0; i < 4; ++i) {
      int lrow = wr * 32 + fm * 16 + kb * 4 + i;
      int r = bm + lrow;
      bool ok = r < M_TOK;
      float s = 0.f, q = 0.f;
#pragma unroll
      for (int fn = 0; fn < 4; ++fn) {
        int c = wc * 64 + fn * 16 + lr;
        float v = acc[fm][fn][i] + bb[fn];
        if (ok) v += srcf[(size_t)r * 256 + c];
        acc[fm][fn][i] = v;
        s += v; q += v * v;
      }
#pragma unroll
      for (int o = 1; o < 16; o <<= 1) {
        s += __shfl_xor(s, o);
        q += __shfl_xor(q, o);
      }
      if (lr == 0) { lns[lrow * 4 + wc] = s; lnq[lrow * 4 + wc] = q; }
    }
  __syncthreads();
#pragma unroll
  for (int fm = 0; fm < 2; ++fm)
#pragma unroll
    for (int i = 0; i < 4; ++i) {
      int lrow = wr * 32 + fm * 16 + kb * 4 + i;
      float S = lns[lrow * 4 + 0] + lns[lrow * 4 + 1] + lns[lrow * 4 + 2] +
                lns[lrow * 4 + 3];
      float Q = lnq[lrow * 4 + 0] + lnq[lrow * 4 + 1] + lnq[lrow * 4 + 2] +
                lnq[lrow * 4 + 3];
      float mean = S * (1.f / 256.f);
      float var = Q * (1.f / 256.f) - mean * mean;
      mean_[fm][i] = mean;
      rs_[fm][i] = rsqrtf(var + 1e-5f);
    }
  float g4[4], lb4[4];
#pragma unroll
  for (int fn = 0; fn < 4; ++fn) {
    int c = wc * 64 + fn * 16 + lr;
    g4[fn] = g[c]; lb4[fn] = lnb[c];
  }
#pragma unroll
  for (int fm = 0; fm < 2; ++fm)
#pragma unroll
    for (int i = 0; i < 4; ++i) {
      int r = bm + wr * 32 + fm * 16 + kb * 4 + i;
      if (r >= M_TOK) continue;
#pragma unroll
      for (int fn = 0; fn < 4; ++fn) {
        int c = wc * 64 + fn * 16 + lr;
        float o = (acc[fm][fn][i] - mean_[fm][i]) * rs_[fm][i] * g4[fn] + lb4[fn];
        if (MODE == 3) {
          outf[(size_t)r * 256 + c] = o;
        } else {
          srcf[(size_t)r * 256 + c] = o;
          srcb[(size_t)r * 256 + c] = f2bf(o);
          if (MODE == 2)
            qb[(size_t)r * 256 + c] = f2bf(o + bf2f(posb[(size_t)r * 256 + c]));
        }
      }
    }
}

// ---------------------------------------------------------------------------
// N=96 GEMM (offsets+attn logits): C f32 = A @ W^T + bias.
// BM=64, BN=128(>=96), BK=64, 256 thr = 2x2 waves of 32x64. Grid: 313.
// (R6 body — no register prefetch.)
// ---------------------------------------------------------------------------
__global__ __launch_bounds__(256) void gemm96(
    const short* __restrict__ A, const short* __restrict__ WT,
    const float* __restrict__ bias, float* __restrict__ Cf) {
  const int N = 96;
  __shared__ short As[64 * 72];
  __shared__ short Bs[128 * 72];
  int tid = threadIdx.x;
  int wave = tid >> 6, lane = tid & 63;
  int lr = lane & 15, kb = lane >> 4;
  int wr = wave >> 1, wc = wave & 1;     // 2 x 2 waves
  int bm = blockIdx.x * 64;

  int arow = tid >> 2, ach = (tid & 3) * 16;   // 64 rows x 4 chunks of 16
  int brow = tid >> 1, bch = (tid & 1) * 32;   // 128 rows x 2 chunks of 32
  bool aok = (bm + arow) < M_TOK;
  bool bok = brow < N;
  const short* aptr = A + (size_t)(bm + arow) * 256 + ach;
  const short* bptr = WT + (size_t)brow * 256 + bch;
  short* asd = &As[arow * 72 + ach];
  short* bsd = &Bs[brow * 72 + bch];

  f32x4 acc[2][4] = {};

  for (int k0 = 0; k0 < 256; k0 += 64) {
    short8v a0 = {}, a1 = {};
    if (aok) {
      a0 = *reinterpret_cast<const short8v*>(aptr + k0);
      a1 = *reinterpret_cast<const short8v*>(aptr + k0 + 8);
    }
    *reinterpret_cast<short8v*>(asd) = a0;
    *reinterpret_cast<short8v*>(asd + 8) = a1;
    short8v b0 = {}, b1 = {}, b2 = {}, b3 = {};
    if (bok) {
      b0 = *reinterpret_cast<const short8v*>(bptr + k0);
      b1 = *reinterpret_cast<const short8v*>(bptr + k0 + 8);
      b2 = *reinterpret_cast<const short8v*>(bptr + k0 + 16);
      b3 = *reinterpret_cast<const short8v*>(bptr + k0 + 24);
    }
    *reinterpret_cast<short8v*>(bsd) = b0;
    *reinterpret_cast<short8v*>(bsd + 8) = b1;
    *reinterpret_cast<short8v*>(bsd + 16) = b2;
    *reinterpret_cast<short8v*>(bsd + 24) = b3;
    __syncthreads();
#pragma unroll
    for (int ks = 0; ks < 2; ++ks) {
      short8v af[2], bf[4];
#pragma unroll
      for (int i = 0; i < 2; ++i)
        af[i] = *reinterpret_cast<const short8v*>(
            &As[(wr * 32 + i * 16 + lr) * 72 + ks * 32 + kb * 8]);
#pragma unroll
      for (int j = 0; j < 4; ++j)
        bf[j] = *reinterpret_cast<const short8v*>(
            &Bs[(wc * 64 + j * 16 + lr) * 72 + ks * 32 + kb * 8]);
#pragma unroll
      for (int i = 0; i < 2; ++i)
#pragma unroll
        for (int j = 0; j < 4; ++j)
          acc[i][j] = __builtin_amdgcn_mfma_f32_16x16x32_bf16(af[i], bf[j],
                                                              acc[i][j], 0, 0, 0);
    }
    __syncthreads();
  }

#pragma unroll
  for (int fn = 0; fn < 4; ++fn) {
    int c = wc * 64 + fn * 16 + lr;
    if (c >= N) continue;
    float bv = bias[c];
#pragma unroll
    for (int fm = 0; fm < 2; ++fm)
#pragma unroll
      for (int i = 0; i < 4; ++i) {
        int r = bm + wr * 32 + fm * 16 + kb * 4 + i;
        if (r < M_TOK) Cf[(size_t)r * N + c] = acc[fm][fn][i] + bv;
      }
  }
}

// ---------------------------------------------------------------------------
// Deformable sampling + fused softmax, bf16 value/attn.
// 256 thr = 8 tokens x 32 lanes; lane: head = lane>>2, d8 = (lane&3)*8.
// Bijective XCD swizzle over 2500 blocks (q=312, r=4).
// ---------------------------------------------------------------------------
__global__ __launch_bounds__(256) void sample_kernel(
    const short* __restrict__ value, const float* __restrict__ offaw,
    short* __restrict__ attn) {
  __shared__ float loff[8][64];
  __shared__ float lw[8][32];
  int bid = blockIdx.x;
  int xcd = bid & 7, idx = bid >> 3;
  int swz = (xcd < 4 ? xcd * 313 : 4 * 313 + (xcd - 4) * 312) + idx;
  int tok0 = swz * 8;
  int tid = threadIdx.x;
  for (int i = tid; i < 768; i += 256) {
    int t = i / 96, j = i - t * 96;
    float v = offaw[(size_t)(tok0 + t) * 96 + j];
    if (j < 64) loff[t][j] = v; else lw[t][j - 64] = v;
  }
  __syncthreads();
  if (tid < 64) {                                   // softmax over 4 points
    int t = tid >> 3, h = tid & 7;
    float* w = &lw[t][h * 4];
    float m = fmaxf(fmaxf(w[0], w[1]), fmaxf(w[2], w[3]));
    float e0 = __expf(w[0] - m), e1 = __expf(w[1] - m);
    float e2 = __expf(w[2] - m), e3 = __expf(w[3] - m);
    float inv = 1.f / (e0 + e1 + e2 + e3);
    w[0] = e0 * inv; w[1] = e1 * inv; w[2] = e2 * inv; w[3] = e3 * inv;
  }
  __syncthreads();

  int ts = tid >> 5, lane = tid & 31;
  int token = tok0 + ts;
  int h = lane >> 2, d8 = (lane & 3) * 8;
  int b = token / S_TOK;
  int s = token - b * S_TOK;
  int ix = s % WID, iy = s / WID;
  const short* vbase = value + ((size_t)b * S_TOK) * D_MODEL + h * DH + d8;

  float acc[8] = {};
#pragma unroll
  for (int p = 0; p < N_POINTS; ++p) {
    float ox = loff[ts][h * 8 + p * 2 + 0];
    float oy = loff[ts][h * 8 + p * 2 + 1];
    float aw = lw[ts][h * 4 + p];
    float px = (float)ix + ox;
    float py = (float)iy + oy;
    float x0f = floorf(px), y0f = floorf(py);
    int x0 = (int)x0f, y0 = (int)y0f;
    float wx1 = px - x0f, wx0 = 1.f - wx1;
    float wy1 = py - y0f, wy0 = 1.f - wy1;
    float sv[8] = {};
    bool xa = (x0 >= 0) & (x0 < WID), xb = (x0 + 1 >= 0) & (x0 + 1 < WID);
    bool ya = (y0 >= 0) & (y0 < HGT), yb = (y0 + 1 >= 0) & (y0 + 1 < HGT);
#define CORNER(XOK, YOK, XI, YI, WGT)                                        \
    if ((XOK) & (YOK)) {                                                     \
      short8v v = *reinterpret_cast<const short8v*>(                         \
          vbase + (size_t)((YI) * WID + (XI)) * D_MODEL);                    \
      float wg = (WGT);                                                      \
      _Pragma("unroll")                                                      \
      for (int j = 0; j < 8; ++j) sv[j] = fmaf(wg, bf2f(v[j]), sv[j]);       \
    }
    CORNER(xa, ya, x0, y0, wx0 * wy0)
    CORNER(xb, ya, x0 + 1, y0, wx1 * wy0)
    CORNER(xa, yb, x0, y0 + 1, wx0 * wy1)
    CORNER(xb, yb, x0 + 1, y0 + 1, wx1 * wy1)
#undef CORNER
#pragma unroll
    for (int j = 0; j < 8; ++j) acc[j] = fmaf(aw, sv[j], acc[j]);
  }
  short8v o;
#pragma unroll
  for (int j = 0; j < 8; ++j) o[j] = f2bf(acc[j]);
  *reinterpret_cast<short8v*>(attn + (size_t)token * D_MODEL + h * DH + d8) = o;
}

// ---------------------------------------------------------------------------
extern "C" void kernel_launch(void* const* d_in, const int* in_sizes, int n_in,
                              void* d_out, int out_size, void* d_ws,
                              size_t ws_size, hipStream_t stream) {
  const float* features  = (const float*)d_in[0];
  const float* pos_embed = (const float*)d_in[1];
  const float* level_emb = (const float*)d_in[2];
  const float* off_w = (const float*)d_in[3];
  const float* off_b = (const float*)d_in[4];
  const float* aw_w  = (const float*)d_in[5];
  const float* aw_b  = (const float*)d_in[6];
  const float* val_w = (const float*)d_in[7];
  const float* val_b = (const float*)d_in[8];
  const float* out_w = (const float*)d_in[9];
  const float* out_b = (const float*)d_in[10];
  const float* ln1_g = (const float*)d_in[11];
  const float* ln1_b = (const float*)d_in[12];
  const float* ffn_w1 = (const float*)d_in[13];
  const float* ffn_b1 = (const float*)d_in[14];
  const float* ffn_w2 = (const float*)d_in[15];
  const float* ffn_b2 = (const float*)d_in[16];
  const float* ln3_g = (const float*)d_in[17];
  const float* ln3_b = (const float*)d_in[18];

  float* ws = (float*)d_ws;
  const size_t BIG = (size_t)M_TOK * D_MODEL;  // 5.12M elems
  float* src   = ws;                           // [M,256] f32 (residual)
  float* offaw = src + BIG;                    // [M,96]  f32
  short* posb  = (short*)(offaw + (size_t)M_TOK * 96);  // [M,256] bf16
  short* srcb  = posb + BIG;                   // [M,256] bf16
  short* qb    = srcb + BIG;                   // [M,256] bf16
  short* value = qb + BIG;                     // [M,256] bf16; reused as hidden
  short* attn  = value + BIG;                  // [M,256] bf16
  short* wv  = attn + BIG;                     // [6][256][256] bf16 (W^T)
  short* wo  = wv + (size_t)6 * 65536;
  short* w1t = wo + (size_t)6 * 65536;
  short* w2t = w1t + (size_t)6 * 65536;
  short* woa = w2t + (size_t)6 * 65536;        // [6][96][256] bf16
  float* bias96 = (float*)(woa + (size_t)6 * 96 * 256);  // [6][96]

  prep_tokens<<<dim3(313, 8, 2), dim3(32, 8), 0, stream>>>(
      features, pos_embed, level_emb, src, posb, srcb, qb);
  prep_weights<<<dim3(8, 8, 36), dim3(32, 8), 0, stream>>>(
      val_w, out_w, ffn_w1, ffn_w2, off_w, aw_w, wv, wo, w1t, w2t, woa);
  biascat_kernel<<<dim3(6), dim3(96), 0, stream>>>(off_b, aw_b, bias96);

  for (int l = 0; l < N_LAYERS; ++l) {
    const short* wvl = wv + (size_t)l * 65536;
    const short* wol = wo + (size_t)l * 65536;
    const short* w1l = w1t + (size_t)l * 65536;
    const short* w2l = w2t + (size_t)l * 65536;
    const short* woal = woa + (size_t)l * 96 * 256;

    // value projection -> value bf16
    gemm_fused<0, 0><<<313, 512, 0, stream>>>(
        srcb, wvl, val_b + (size_t)l * 256, value, nullptr, nullptr, nullptr,
        nullptr, nullptr, nullptr, nullptr);
    // offsets + attn logits -> offaw f32
    gemm96<<<313, 256, 0, stream>>>(qb, woal, bias96 + (size_t)l * 96, offaw);
    // deformable sampling -> attn bf16
    sample_kernel<<<M_TOK / 8, 256, 0, stream>>>(value, offaw, attn);
    // out-proj + residual + LN1 -> src f32, srcb bf16
    gemm_fused<0, 1><<<313, 512, 0, stream>>>(
        attn, wol, out_b + (size_t)l * 256, nullptr, src, nullptr, srcb,
        nullptr, nullptr, ln1_g + l * 256, ln1_b + l * 256);
    // FFN1 + ReLU -> hidden bf16 (reuse value buffer)
    gemm_fused<1, 0><<<313, 512, 0, stream>>>(
        srcb, w1l, ffn_b1 + (size_t)l * 256, value, nullptr, nullptr, nullptr,
        nullptr, nullptr, nullptr, nullptr);
    // FFN2 + residual + LN3 -> src/srcb/qb  (last layer: d_out f32 only)
    if (l == N_LAYERS - 1) {
      gemm_fused<0, 3><<<313, 512, 0, stream>>>(
          value, w2l, ffn_b2 + (size_t)l * 256, nullptr, src, (float*)d_out,
          nullptr, nullptr, nullptr, ln3_g + l * 256, ln3_b + l * 256);
    } else {
      gemm_fused<0, 2><<<313, 512, 0, stream>>>(
          value, w2l, ffn_b2 + (size_t)l * 256, nullptr, src, nullptr, srcb,
          qb, posb, ln3_g + l * 256, ln3_b + l * 256);
    }
  }
}

// Round 11
// 558.859 us; speedup vs baseline: 3.2346x; 1.1088x over previous
//
#include <hip/hip_runtime.h>
#include <math.h>

#define HGT 100
#define WID 100
#define S_TOK (HGT * WID)          // 10000
#define D_MODEL 256
#define N_HEADS 8
#define DH 32
#define N_POINTS 4
#define N_LAYERS 6
#define BS 2
#define M_TOK (BS * S_TOK)         // 20000

typedef __attribute__((ext_vector_type(8))) short short8v;   // 8 bf16 = 16 B
typedef __attribute__((ext_vector_type(4))) short short4v;   // 4 bf16 = 8 B
typedef __attribute__((ext_vector_type(4))) float f32x4;

__device__ __forceinline__ short f2bf(float f) {
  union { float f; unsigned u; } v; v.f = f;
  unsigned r = v.u + 0x7fff + ((v.u >> 16) & 1);   // round-to-nearest-even
  return (short)(r >> 16);
}
__device__ __forceinline__ float bf2f(short s) {
  union { unsigned u; float f; } v;
  v.u = ((unsigned)(unsigned short)s) << 16;
  return v.f;
}

// ---------------------------------------------------------------------------
// Fused token prep: transpose [bs,C,S]->[bs,S,C] for features AND pos; emit
// posb bf16 (pos+level), srcb bf16(features), qb bf16(src+posb).
// grid (313, 8, 2) block (32,8)
// ---------------------------------------------------------------------------
__global__ __launch_bounds__(256) void prep_tokens(
    const float* __restrict__ feat, const float* __restrict__ posin,
    const float* __restrict__ level, short* __restrict__ posb,
    short* __restrict__ srcb, short* __restrict__ qb) {
  __shared__ float tf[32][33];
  __shared__ float tp[32][33];
  int b = blockIdx.z;
  int s0 = blockIdx.x * 32;
  int c0 = blockIdx.y * 32;
  int tx = threadIdx.x, ty = threadIdx.y;
#pragma unroll
  for (int i = 0; i < 4; ++i) {
    int c = c0 + ty + i * 8;
    int s = s0 + tx;
    bool ok = s < S_TOK;
    size_t o = ((size_t)b * D_MODEL + c) * S_TOK + s;
    tf[ty + i * 8][tx] = ok ? feat[o] : 0.f;
    tp[ty + i * 8][tx] = ok ? posin[o] : 0.f;
  }
  __syncthreads();
#pragma unroll
  for (int i = 0; i < 4; ++i) {
    int s = s0 + ty + i * 8;
    int c = c0 + tx;
    if (s < S_TOK) {
      float f = tf[tx][ty + i * 8];
      float p = tp[tx][ty + i * 8] + level[c];
      size_t o = ((size_t)b * S_TOK + s) * D_MODEL + c;
      short pb = f2bf(p);
      posb[o] = pb;
      srcb[o] = f2bf(f);
      qb[o] = f2bf(f + bf2f(pb));
    }
  }
}

// ---------------------------------------------------------------------------
// Fused weight prep: transpose + fp32->bf16 for all 6 weight groups.
// grid (8, 8, 36): z = l*6 + widx. widx 0..3: 256-col weights; 4: off (64);
// 5: aw (32, dst rows offset +64 in woa).
// ---------------------------------------------------------------------------
__global__ __launch_bounds__(256) void prep_weights(
    const float* __restrict__ val_w, const float* __restrict__ out_w,
    const float* __restrict__ ffn_w1, const float* __restrict__ ffn_w2,
    const float* __restrict__ off_w, const float* __restrict__ aw_w,
    short* __restrict__ wv, short* __restrict__ wo, short* __restrict__ w1t,
    short* __restrict__ w2t, short* __restrict__ woa) {
  int z = blockIdx.z;
  int l = z / 6, widx = z - (z / 6) * 6;
  const float* s;
  short* d;
  int N;
  if (widx == 0)      { s = val_w  + (size_t)l * 65536; d = wv  + (size_t)l * 65536; N = 256; }
  else if (widx == 1) { s = out_w  + (size_t)l * 65536; d = wo  + (size_t)l * 65536; N = 256; }
  else if (widx == 2) { s = ffn_w1 + (size_t)l * 65536; d = w1t + (size_t)l * 65536; N = 256; }
  else if (widx == 3) { s = ffn_w2 + (size_t)l * 65536; d = w2t + (size_t)l * 65536; N = 256; }
  else if (widx == 4) { s = off_w + (size_t)l * 256 * 64; d = woa + (size_t)l * 96 * 256; N = 64; }
  else                { s = aw_w  + (size_t)l * 256 * 32; d = woa + (size_t)l * 96 * 256 + (size_t)64 * 256; N = 32; }
  int n0 = blockIdx.x * 32, k0 = blockIdx.y * 32;
  if (n0 >= N) return;
  __shared__ float t[32][33];
  int tx = threadIdx.x, ty = threadIdx.y;
#pragma unroll
  for (int i = 0; i < 4; ++i) {
    int k = k0 + ty + i * 8;
    int n = n0 + tx;
    t[ty + i * 8][tx] = (n < N) ? s[(size_t)k * N + n] : 0.f;
  }
  __syncthreads();
#pragma unroll
  for (int i = 0; i < 4; ++i) {
    int n = n0 + ty + i * 8;
    int k = k0 + tx;
    if (n < N) d[(size_t)n * 256 + k] = f2bf(t[tx][ty + i * 8]);
  }
}

__global__ void biascat_kernel(const float* __restrict__ ob,
                               const float* __restrict__ ab,
                               float* __restrict__ dst) {
  int l = blockIdx.x, i = threadIdx.x;
  dst[l * 96 + i] = (i < 64) ? ob[l * 64 + i] : ab[l * 32 + (i - 64)];
}

// ---------------------------------------------------------------------------
// Unified bf16 MFMA GEMM, BM=64, BN=N=K=256, 512 thr = 8 waves (2x4),
// wave tile 32x64 (2x4 16x16x32 frags), fp32 accumulate. Grid: 313.
// (R9 sync structure — no register prefetch.)
// MODE 0: C = A@W^T + bias (+ReLU if ACT) -> Cb bf16.
// MODE 1: LN(bf16 resid + C) -> resid bf16 (in-place).
// MODE 2: MODE 1 + qb = bf16(out + posb).
// MODE 3: LN(bf16 resid + C) -> outf f32 only (final output).
// ---------------------------------------------------------------------------
template <int ACT, int MODE>
__global__ __launch_bounds__(512) void gemm_fused(
    const short* __restrict__ A, const short* __restrict__ WT,
    const float* __restrict__ bias, short* __restrict__ Cb,
    short* __restrict__ resid, float* __restrict__ outf,
    short* __restrict__ qb, const short* __restrict__ posb,
    const float* __restrict__ g, const float* __restrict__ lnb) {
  __shared__ short As[64 * 72];
  __shared__ short Bs[256 * 72];
  int tid = threadIdx.x;
  int wave = tid >> 6, lane = tid & 63;
  int lr = lane & 15, kb = lane >> 4;
  int wr = wave >> 2, wc = wave & 3;     // 2 x 4 waves
  int bm = blockIdx.x * 64;

  int arow = tid >> 3, ach = (tid & 7) * 8;    // 64 rows x 8 chunks of 8
  int brow = tid >> 1, bch = (tid & 1) * 32;   // 256 rows x 2 chunks of 32
  bool aok = (bm + arow) < M_TOK;
  const short* aptr = A + (size_t)(bm + arow) * 256 + ach;
  const short* bptr = WT + (size_t)brow * 256 + bch;
  short* asd = &As[arow * 72 + ach];
  short* bsd = &Bs[brow * 72 + bch];

  f32x4 acc[2][4] = {};

  for (int k0 = 0; k0 < 256; k0 += 64) {
    short8v a0 = {};
    if (aok) a0 = *reinterpret_cast<const short8v*>(aptr + k0);
    *reinterpret_cast<short8v*>(asd) = a0;
#pragma unroll
    for (int j = 0; j < 4; ++j)
      *reinterpret_cast<short8v*>(bsd + j * 8) =
          *reinterpret_cast<const short8v*>(bptr + k0 + j * 8);
    __syncthreads();
#pragma unroll
    for (int ks = 0; ks < 2; ++ks) {
      short8v af[2], bf[4];
#pragma unroll
      for (int i = 0; i < 2; ++i)
        af[i] = *reinterpret_cast<const short8v*>(
            &As[(wr * 32 + i * 16 + lr) * 72 + ks * 32 + kb * 8]);
#pragma unroll
      for (int j = 0; j < 4; ++j)
        bf[j] = *reinterpret_cast<const short8v*>(
            &Bs[(wc * 64 + j * 16 + lr) * 72 + ks * 32 + kb * 8]);
#pragma unroll
      for (int i = 0; i < 2; ++i)
#pragma unroll
        for (int j = 0; j < 4; ++j)
          acc[i][j] = __builtin_amdgcn_mfma_f32_16x16x32_bf16(af[i], bf[j],
                                                              acc[i][j], 0, 0, 0);
    }
    __syncthreads();
  }

  float bb[4];
#pragma unroll
  for (int fn = 0; fn < 4; ++fn) bb[fn] = bias[wc * 64 + fn * 16 + lr];

  if (MODE == 0) {
#pragma unroll
    for (int fm = 0; fm < 2; ++fm)
#pragma unroll
      for (int i = 0; i < 4; ++i) {
        int r = bm + wr * 32 + fm * 16 + kb * 4 + i;
        if (r >= M_TOK) continue;
#pragma unroll
        for (int fn = 0; fn < 4; ++fn) {
          int c = wc * 64 + fn * 16 + lr;
          float v = acc[fm][fn][i] + bb[fn];
          if (ACT) v = fmaxf(v, 0.f);
          Cb[(size_t)r * 256 + c] = f2bf(v);
        }
      }
    return;
  }

  // ---- fused residual (bf16) + LayerNorm epilogue ----
  float* lns = (float*)As;           // [64][4] row partial sums
  float* lnq = lns + 256;            // [64][4] row partial sumsq
  float mean_[2][4], rs_[2][4];
#pragma unroll
  for (int fm = 0; fm < 2; ++fm)
#pragma unroll
    for (int i = 0; i < 4; ++i) {
      int lrow = wr * 32 + fm * 16 + kb * 4 + i;
      int r = bm + lrow;
      bool ok = r < M_TOK;
      float s = 0.f, q = 0.f;
#pragma unroll
      for (int fn = 0; fn < 4; ++fn) {
        int c = wc * 64 + fn * 16 + lr;
        float v = acc[fm][fn][i] + bb[fn];
        if (ok) v += bf2f(resid[(size_t)r * 256 + c]);
        acc[fm][fn][i] = v;
        s += v; q += v * v;
      }
#pragma unroll
      for (int o = 1; o < 16; o <<= 1) {
        s += __shfl_xor(s, o);
        q += __shfl_xor(q, o);
      }
      if (lr == 0) { lns[lrow * 4 + wc] = s; lnq[lrow * 4 + wc] = q; }
    }
  __syncthreads();
#pragma unroll
  for (int fm = 0; fm < 2; ++fm)
#pragma unroll
    for (int i = 0; i < 4; ++i) {
      int lrow = wr * 32 + fm * 16 + kb * 4 + i;
      float S = lns[lrow * 4 + 0] + lns[lrow * 4 + 1] + lns[lrow * 4 + 2] +
                lns[lrow * 4 + 3];
      float Q = lnq[lrow * 4 + 0] + lnq[lrow * 4 + 1] + lnq[lrow * 4 + 2] +
                lnq[lrow * 4 + 3];
      float mean = S * (1.f / 256.f);
      float var = Q * (1.f / 256.f) - mean * mean;
      mean_[fm][i] = mean;
      rs_[fm][i] = rsqrtf(var + 1e-5f);
    }
  float g4[4], lb4[4];
#pragma unroll
  for (int fn = 0; fn < 4; ++fn) {
    int c = wc * 64 + fn * 16 + lr;
    g4[fn] = g[c]; lb4[fn] = lnb[c];
  }
#pragma unroll
  for (int fm = 0; fm < 2; ++fm)
#pragma unroll
    for (int i = 0; i < 4; ++i) {
      int r = bm + wr * 32 + fm * 16 + kb * 4 + i;
      if (r >= M_TOK) continue;
#pragma unroll
      for (int fn = 0; fn < 4; ++fn) {
        int c = wc * 64 + fn * 16 + lr;
        float o = (acc[fm][fn][i] - mean_[fm][i]) * rs_[fm][i] * g4[fn] + lb4[fn];
        if (MODE == 3) {
          outf[(size_t)r * 256 + c] = o;
        } else {
          resid[(size_t)r * 256 + c] = f2bf(o);
          if (MODE == 2)
            qb[(size_t)r * 256 + c] = f2bf(o + bf2f(posb[(size_t)r * 256 + c]));
        }
      }
    }
}

// ---------------------------------------------------------------------------
// N=96 GEMM (offsets+attn logits): C f32 = A @ W^T + bias.
// BM=64, BN=128(>=96), BK=64, 256 thr = 2x2 waves of 32x64. Grid: 313.
// ---------------------------------------------------------------------------
__global__ __launch_bounds__(256) void gemm96(
    const short* __restrict__ A, const short* __restrict__ WT,
    const float* __restrict__ bias, float* __restrict__ Cf) {
  const int N = 96;
  __shared__ short As[64 * 72];
  __shared__ short Bs[128 * 72];
  int tid = threadIdx.x;
  int wave = tid >> 6, lane = tid & 63;
  int lr = lane & 15, kb = lane >> 4;
  int wr = wave >> 1, wc = wave & 1;     // 2 x 2 waves
  int bm = blockIdx.x * 64;

  int arow = tid >> 2, ach = (tid & 3) * 16;   // 64 rows x 4 chunks of 16
  int brow = tid >> 1, bch = (tid & 1) * 32;   // 128 rows x 2 chunks of 32
  bool aok = (bm + arow) < M_TOK;
  bool bok = brow < N;
  const short* aptr = A + (size_t)(bm + arow) * 256 + ach;
  const short* bptr = WT + (size_t)brow * 256 + bch;
  short* asd = &As[arow * 72 + ach];
  short* bsd = &Bs[brow * 72 + bch];

  f32x4 acc[2][4] = {};

  for (int k0 = 0; k0 < 256; k0 += 64) {
    short8v a0 = {}, a1 = {};
    if (aok) {
      a0 = *reinterpret_cast<const short8v*>(aptr + k0);
      a1 = *reinterpret_cast<const short8v*>(aptr + k0 + 8);
    }
    *reinterpret_cast<short8v*>(asd) = a0;
    *reinterpret_cast<short8v*>(asd + 8) = a1;
    short8v b0 = {}, b1 = {}, b2 = {}, b3 = {};
    if (bok) {
      b0 = *reinterpret_cast<const short8v*>(bptr + k0);
      b1 = *reinterpret_cast<const short8v*>(bptr + k0 + 8);
      b2 = *reinterpret_cast<const short8v*>(bptr + k0 + 16);
      b3 = *reinterpret_cast<const short8v*>(bptr + k0 + 24);
    }
    *reinterpret_cast<short8v*>(bsd) = b0;
    *reinterpret_cast<short8v*>(bsd + 8) = b1;
    *reinterpret_cast<short8v*>(bsd + 16) = b2;
    *reinterpret_cast<short8v*>(bsd + 24) = b3;
    __syncthreads();
#pragma unroll
    for (int ks = 0; ks < 2; ++ks) {
      short8v af[2], bf[4];
#pragma unroll
      for (int i = 0; i < 2; ++i)
        af[i] = *reinterpret_cast<const short8v*>(
            &As[(wr * 32 + i * 16 + lr) * 72 + ks * 32 + kb * 8]);
#pragma unroll
      for (int j = 0; j < 4; ++j)
        bf[j] = *reinterpret_cast<const short8v*>(
            &Bs[(wc * 64 + j * 16 + lr) * 72 + ks * 32 + kb * 8]);
#pragma unroll
      for (int i = 0; i < 2; ++i)
#pragma unroll
        for (int j = 0; j < 4; ++j)
          acc[i][j] = __builtin_amdgcn_mfma_f32_16x16x32_bf16(af[i], bf[j],
                                                              acc[i][j], 0, 0, 0);
    }
    __syncthreads();
  }

#pragma unroll
  for (int fn = 0; fn < 4; ++fn) {
    int c = wc * 64 + fn * 16 + lr;
    if (c >= N) continue;
    float bv = bias[c];
#pragma unroll
    for (int fm = 0; fm < 2; ++fm)
#pragma unroll
      for (int i = 0; i < 4; ++i) {
        int r = bm + wr * 32 + fm * 16 + kb * 4 + i;
        if (r < M_TOK) Cf[(size_t)r * N + c] = acc[fm][fn][i] + bv;
      }
  }
}

// ---------------------------------------------------------------------------
// Deformable sampling + fused softmax, bf16 value/attn.
// 256 thr = 8 tokens x 32 lanes; lane: head = lane>>2, d8 = (lane&3)*8.
// Bijective XCD swizzle over 2500 blocks (q=312, r=4).
// ---------------------------------------------------------------------------
__global__ __launch_bounds__(256) void sample_kernel(
    const short* __restrict__ value, const float* __restrict__ offaw,
    short* __restrict__ attn) {
  __shared__ float loff[8][64];
  __shared__ float lw[8][32];
  int bid = blockIdx.x;
  int xcd = bid & 7, idx = bid >> 3;
  int swz = (xcd < 4 ? xcd * 313 : 4 * 313 + (xcd - 4) * 312) + idx;
  int tok0 = swz * 8;
  int tid = threadIdx.x;
  for (int i = tid; i < 768; i += 256) {
    int t = i / 96, j = i - t * 96;
    float v = offaw[(size_t)(tok0 + t) * 96 + j];
    if (j < 64) loff[t][j] = v; else lw[t][j - 64] = v;
  }
  __syncthreads();
  if (tid < 64) {                                   // softmax over 4 points
    int t = tid >> 3, h = tid & 7;
    float* w = &lw[t][h * 4];
    float m = fmaxf(fmaxf(w[0], w[1]), fmaxf(w[2], w[3]));
    float e0 = __expf(w[0] - m), e1 = __expf(w[1] - m);
    float e2 = __expf(w[2] - m), e3 = __expf(w[3] - m);
    float inv = 1.f / (e0 + e1 + e2 + e3);
    w[0] = e0 * inv; w[1] = e1 * inv; w[2] = e2 * inv; w[3] = e3 * inv;
  }
  __syncthreads();

  int ts = tid >> 5, lane = tid & 31;
  int token = tok0 + ts;
  int h = lane >> 2, d8 = (lane & 3) * 8;
  int b = token / S_TOK;
  int s = token - b * S_TOK;
  int ix = s % WID, iy = s / WID;
  const short* vbase = value + ((size_t)b * S_TOK) * D_MODEL + h * DH + d8;

  float acc[8] = {};
#pragma unroll
  for (int p = 0; p < N_POINTS; ++p) {
    float ox = loff[ts][h * 8 + p * 2 + 0];
    float oy = loff[ts][h * 8 + p * 2 + 1];
    float aw = lw[ts][h * 4 + p];
    float px = (float)ix + ox;
    float py = (float)iy + oy;
    float x0f = floorf(px), y0f = floorf(py);
    int x0 = (int)x0f, y0 = (int)y0f;
    float wx1 = px - x0f, wx0 = 1.f - wx1;
    float wy1 = py - y0f, wy0 = 1.f - wy1;
    float sv[8] = {};
    bool xa = (x0 >= 0) & (x0 < WID), xb = (x0 + 1 >= 0) & (x0 + 1 < WID);
    bool ya = (y0 >= 0) & (y0 < HGT), yb = (y0 + 1 >= 0) & (y0 + 1 < HGT);
#define CORNER(XOK, YOK, XI, YI, WGT)                                        \
    if ((XOK) & (YOK)) {                                                     \
      short8v v = *reinterpret_cast<const short8v*>(                         \
          vbase + (size_t)((YI) * WID + (XI)) * D_MODEL);                    \
      float wg = (WGT);                                                      \
      _Pragma("unroll")                                                      \
      for (int j = 0; j < 8; ++j) sv[j] = fmaf(wg, bf2f(v[j]), sv[j]);       \
    }
    CORNER(xa, ya, x0, y0, wx0 * wy0)
    CORNER(xb, ya, x0 + 1, y0, wx1 * wy0)
    CORNER(xa, yb, x0, y0 + 1, wx0 * wy1)
    CORNER(xb, yb, x0 + 1, y0 + 1, wx1 * wy1)
#undef CORNER
#pragma unroll
    for (int j = 0; j < 8; ++j) acc[j] = fmaf(aw, sv[j], acc[j]);
  }
  short8v o;
#pragma unroll
  for (int j = 0; j < 8; ++j) o[j] = f2bf(acc[j]);
  *reinterpret_cast<short8v*>(attn + (size_t)token * D_MODEL + h * DH + d8) = o;
}

// ---------------------------------------------------------------------------
extern "C" void kernel_launch(void* const* d_in, const int* in_sizes, int n_in,
                              void* d_out, int out_size, void* d_ws,
                              size_t ws_size, hipStream_t stream) {
  const float* features  = (const float*)d_in[0];
  const float* pos_embed = (const float*)d_in[1];
  const float* level_emb = (const float*)d_in[2];
  const float* off_w = (const float*)d_in[3];
  const float* off_b = (const float*)d_in[4];
  const float* aw_w  = (const float*)d_in[5];
  const float* aw_b  = (const float*)d_in[6];
  const float* val_w = (const float*)d_in[7];
  const float* val_b = (const float*)d_in[8];
  const float* out_w = (const float*)d_in[9];
  const float* out_b = (const float*)d_in[10];
  const float* ln1_g = (const float*)d_in[11];
  const float* ln1_b = (const float*)d_in[12];
  const float* ffn_w1 = (const float*)d_in[13];
  const float* ffn_b1 = (const float*)d_in[14];
  const float* ffn_w2 = (const float*)d_in[15];
  const float* ffn_b2 = (const float*)d_in[16];
  const float* ln3_g = (const float*)d_in[17];
  const float* ln3_b = (const float*)d_in[18];

  float* ws = (float*)d_ws;
  const size_t BIG = (size_t)M_TOK * D_MODEL;  // 5.12M elems
  float* offaw = ws;                           // [M,96]  f32
  short* posb  = (short*)(offaw + (size_t)M_TOK * 96);  // [M,256] bf16
  short* srcb  = posb + BIG;                   // [M,256] bf16 (residual state)
  short* qb    = srcb + BIG;                   // [M,256] bf16
  short* value = qb + BIG;                     // [M,256] bf16; reused as hidden
  short* attn  = value + BIG;                  // [M,256] bf16
  short* wv  = attn + BIG;                     // [6][256][256] bf16 (W^T)
  short* wo  = wv + (size_t)6 * 65536;
  short* w1t = wo + (size_t)6 * 65536;
  short* w2t = w1t + (size_t)6 * 65536;
  short* woa = w2t + (size_t)6 * 65536;        // [6][96][256] bf16
  float* bias96 = (float*)(woa + (size_t)6 * 96 * 256);  // [6][96]

  prep_tokens<<<dim3(313, 8, 2), dim3(32, 8), 0, stream>>>(
      features, pos_embed, level_emb, posb, srcb, qb);
  prep_weights<<<dim3(8, 8, 36), dim3(32, 8), 0, stream>>>(
      val_w, out_w, ffn_w1, ffn_w2, off_w, aw_w, wv, wo, w1t, w2t, woa);
  biascat_kernel<<<dim3(6), dim3(96), 0, stream>>>(off_b, aw_b, bias96);

  for (int l = 0; l < N_LAYERS; ++l) {
    const short* wvl = wv + (size_t)l * 65536;
    const short* wol = wo + (size_t)l * 65536;
    const short* w1l = w1t + (size_t)l * 65536;
    const short* w2l = w2t + (size_t)l * 65536;
    const short* woal = woa + (size_t)l * 96 * 256;

    // value projection -> value bf16
    gemm_fused<0, 0><<<313, 512, 0, stream>>>(
        srcb, wvl, val_b + (size_t)l * 256, value, nullptr, nullptr, nullptr,
        nullptr, nullptr, nullptr);
    // offsets + attn logits -> offaw f32
    gemm96<<<313, 256, 0, stream>>>(qb, woal, bias96 + (size_t)l * 96, offaw);
    // deformable sampling -> attn bf16
    sample_kernel<<<M_TOK / 8, 256, 0, stream>>>(value, offaw, attn);
    // out-proj + residual + LN1 -> srcb (in-place)
    gemm_fused<0, 1><<<313, 512, 0, stream>>>(
        attn, wol, out_b + (size_t)l * 256, nullptr, srcb, nullptr, nullptr,
        nullptr, ln1_g + l * 256, ln1_b + l * 256);
    // FFN1 + ReLU -> hidden bf16 (reuse value buffer)
    gemm_fused<1, 0><<<313, 512, 0, stream>>>(
        srcb, w1l, ffn_b1 + (size_t)l * 256, value, nullptr, nullptr, nullptr,
        nullptr, nullptr, nullptr);
    // FFN2 + residual + LN3 -> srcb/qb  (last layer: d_out f32 only)
    if (l == N_LAYERS - 1) {
      gemm_fused<0, 3><<<313, 512, 0, stream>>>(
          value, w2l, ffn_b2 + (size_t)l * 256, nullptr, srcb, (float*)d_out,
          nullptr, nullptr, ln3_g + l * 256, ln3_b + l * 256);
    } else {
      gemm_fused<0, 2><<<313, 512, 0, stream>>>(
          value, w2l, ffn_b2 + (size_t)l * 256, nullptr, srcb, nullptr,
          qb, posb, ln3_g + l * 256, ln3_b + l * 256);
    }
  }
}